// Round 2
// baseline (2583.918 us; speedup 1.0000x reference)
//
#include <hip/hip_runtime.h>
#include <hip/hip_bf16.h>
#include <math.h>

#define TOKENS 8192
#define HDIM 1152
#define SEQ 2048
#define NHEADS 12
#define HEADD 96
#define NMEM 4
#define MEMD 128
#define FINNER 4608

typedef __hip_bfloat16 bf16;
typedef __attribute__((ext_vector_type(8))) short short8;
typedef __attribute__((ext_vector_type(4))) float floatx4;

__device__ __constant__ int g_hd_dil[NHEADS * 3] = {
    1, 2, 4,   1, 1, 1,    4, 8, 16,   8, 16, 32,
    32, 64, 128, 64, 128, 256, 256, 512, 1024, 1, 100, 200,
    1, 500, 1000, 1, 1024, 2048, 3, 9, 27, 5, 25, 125};

__device__ inline float sigm(float x) { return 1.0f / (1.0f + expf(-x)); }
__device__ inline float gelu_exact(float x) {
  return 0.5f * x * (1.0f + erff(x * 0.70710678118654752f));
}
__device__ inline float wred(float v) {
#pragma unroll
  for (int o = 32; o > 0; o >>= 1) v += __shfl_down(v, o);
  return v;
}

// ---------------- transpose f32 [K,N] -> bf16 [N,K] ----------------
__global__ __launch_bounds__(256) void k_transpose_bf16(
    const float* __restrict__ W, bf16* __restrict__ WT, int K, int N) {
  __shared__ float t[32][33];
  int k0 = blockIdx.y * 32, n0 = blockIdx.x * 32;
  int tx = threadIdx.x & 31, ty = threadIdx.x >> 5;  // ty 0..7
#pragma unroll
  for (int i = 0; i < 32; i += 8)
    t[ty + i][tx] = W[(size_t)(k0 + ty + i) * N + (n0 + tx)];
  __syncthreads();
#pragma unroll
  for (int i = 0; i < 32; i += 8)
    WT[(size_t)(n0 + ty + i) * K + (k0 + tx)] = __float2bfloat16(t[tx][ty + i]);
}

// ---- pair-permuted transpose: out row 2c = W[:,c], row 2c+1 = W[:,half+c] ----
__global__ __launch_bounds__(256) void k_transpose_pair(
    const float* __restrict__ W, bf16* __restrict__ WT, int K, int N) {
  __shared__ float t[32][33];
  int half = N >> 1;
  int k0 = blockIdx.y * 32, n0 = blockIdx.x * 32;
  int tx = threadIdx.x & 31, ty = threadIdx.x >> 5;
  int c = (tx < 16) ? (n0 / 2 + tx) : (half + n0 / 2 + tx - 16);
#pragma unroll
  for (int i = 0; i < 32; i += 8)
    t[ty + i][tx] = W[(size_t)(k0 + ty + i) * N + c];
  __syncthreads();
#pragma unroll
  for (int i = 0; i < 32; i += 8) {
    int r = ty + i;
    int cc = (r >> 1) + (r & 1) * 16;
    WT[(size_t)(n0 + r) * K + (k0 + tx)] = __float2bfloat16(t[tx][cc]);
  }
}

// ---------------- rmsnorm + scalar gate ----------------
__global__ __launch_bounds__(256) void k_rms_gate(
    const float* __restrict__ x, const float* __restrict__ nw,
    const float* __restrict__ gw, const float* __restrict__ gb,
    bf16* __restrict__ outb, float* outf, float* __restrict__ gout,
    int writef) {
  __shared__ float r1[4], r2[4];
  int tok = blockIdx.x;
  int tid = threadIdx.x;
  const float* row = x + (size_t)tok * HDIM;
  float s2 = 0.f, gd = 0.f;
  for (int i = tid; i < HDIM; i += 256) {
    float a = row[i];
    s2 += a * a;
    gd += a * gw[i];
  }
  s2 = wred(s2);
  gd = wred(gd);
  int wave = tid >> 6, lane = tid & 63;
  if (lane == 0) {
    r1[wave] = s2;
    r2[wave] = gd;
  }
  __syncthreads();
  s2 = r1[0] + r1[1] + r1[2] + r1[3];
  gd = r2[0] + r2[1] + r2[2] + r2[3];
  float rn = 1.0f / sqrtf(s2 / (float)HDIM + 1e-6f);
  if (tid == 0) gout[tok] = sigm(gd + gb[0]);
  for (int i = tid; i < HDIM; i += 256) {
    float a = row[i] * rn * nw[i];
    outb[(size_t)tok * HDIM + i] = __float2bfloat16(a);
    if (writef) outf[(size_t)tok * HDIM + i] = a;
  }
}

// ---------------- conv-stack step: h = h + gelu(dconv(h)) ----------------
__global__ __launch_bounds__(256) void k_dconv_gelu(
    const float* __restrict__ hin, float* __restrict__ hout,
    const float* __restrict__ w, const float* __restrict__ b, int d) {
  size_t idx = (size_t)blockIdx.x * 256 + threadIdx.x;
  if (idx >= (size_t)TOKENS * HDIM) return;
  int c = (int)(idx % HDIM);
  size_t tok = idx / HDIM;
  int s = (int)(tok % SEQ);
  float acc = b[c];
#pragma unroll
  for (int j = 0; j < 4; ++j) {
    int back = (3 - j) * d;
    if (s - back >= 0) acc += w[c * 4 + j] * hin[idx - (size_t)back * HDIM];
  }
  hout[idx] = hin[idx] + gelu_exact(acc);
}

// ---------------- per-head conv step j: h = h + dconv(h) ----------------
__global__ __launch_bounds__(256) void k_headconv(
    const float* __restrict__ hin, float* __restrict__ hout,
    const float* __restrict__ hw_, const float* __restrict__ hb_, int j) {
  size_t idx = (size_t)blockIdx.x * 256 + threadIdx.x;
  if (idx >= (size_t)TOKENS * HDIM) return;
  int c = (int)(idx % HDIM);
  int head = c / HEADD, hd = c % HEADD;
  size_t tok = idx / HDIM;
  int s = (int)(tok % SEQ);
  int d = g_hd_dil[head * 3 + j];
  const float* w = hw_ + ((size_t)(head * 3 + j) * HEADD + hd) * 4;
  float acc = hb_[(head * 3 + j) * HEADD + hd];
#pragma unroll
  for (int jj = 0; jj < 4; ++jj) {
    int back = (3 - jj) * d;
    if (s - back >= 0) acc += w[jj] * hin[idx - (size_t)back * HDIM];
  }
  hout[idx] = hin[idx] + acc;
}

// ---------------- GEMM: C[M,N] = A[M,K](bf16) * BT[N,K](bf16)^T ----------------
// MODE 0: store f32            MODE 1: store bf16
// MODE 2: out = addin + gate[m]*(acc+bias)    MODE 3: sigmoid -> f32
// MODE 4: pair-GLU (even col a, odd col g) -> a*sigm(g) f32, N halves
// MODE 5: pair-GLU -> bf16
template <int MODE>
__global__ __launch_bounds__(256) void k_gemm(
    const bf16* __restrict__ A, const bf16* __restrict__ BT,
    const float* __restrict__ bias, const float* __restrict__ gate,
    const float* addin, float* outf, bf16* outb, int M, int N, int K) {
  __shared__ bf16 As[128 * 40];
  __shared__ bf16 Bs[128 * 40];
  const int tid = threadIdx.x;
  const int m0 = blockIdx.y * 128, n0 = blockIdx.x * 128;
  const int wave = tid >> 6, lane = tid & 63;
  const int wm = (wave & 1) * 64, wn = (wave >> 1) * 64;
  const int l16 = lane & 15, kq = lane >> 4;
  const int srow = tid >> 2, schunk = (tid & 3) * 8;
  floatx4 acc[4][4];
  floatx4 zero = {0.f, 0.f, 0.f, 0.f};
#pragma unroll
  for (int i = 0; i < 4; ++i)
#pragma unroll
    for (int jj = 0; jj < 4; ++jj) acc[i][jj] = zero;

  for (int k0 = 0; k0 < K; k0 += 32) {
    __syncthreads();
#pragma unroll
    for (int h = 0; h < 2; ++h) {
      int r = srow + h * 64;
      *reinterpret_cast<int4*>(&As[r * 40 + schunk]) =
          *reinterpret_cast<const int4*>(&A[(size_t)(m0 + r) * K + k0 + schunk]);
      *reinterpret_cast<int4*>(&Bs[r * 40 + schunk]) =
          *reinterpret_cast<const int4*>(&BT[(size_t)(n0 + r) * K + k0 + schunk]);
    }
    __syncthreads();
    short8 af[4], bfr[4];
#pragma unroll
    for (int t = 0; t < 4; ++t) {
      af[t] = *reinterpret_cast<const short8*>(&As[(wm + t * 16 + l16) * 40 + kq * 8]);
      bfr[t] = *reinterpret_cast<const short8*>(&Bs[(wn + t * 16 + l16) * 40 + kq * 8]);
    }
#pragma unroll
    for (int mt = 0; mt < 4; ++mt)
#pragma unroll
      for (int nt = 0; nt < 4; ++nt)
        acc[mt][nt] = __builtin_amdgcn_mfma_f32_16x16x32_bf16(
            af[mt], bfr[nt], acc[mt][nt], 0, 0, 0);
  }

  if (MODE == 4 || MODE == 5) {
    const int halfN = N >> 1;
#pragma unroll
    for (int mt = 0; mt < 4; ++mt) {
#pragma unroll
      for (int nt = 0; nt < 4; ++nt) {
        int nn = n0 + wn + nt * 16 + l16;
#pragma unroll
        for (int r = 0; r < 4; ++r) {
          float v = acc[mt][nt][r];
          float g = __shfl_xor(v, 1);
          if ((lane & 1) == 0) {
            int m = m0 + wm + mt * 16 + kq * 4 + r;
            float res = v * sigm(g);
            size_t o = (size_t)m * halfN + (nn >> 1);
            if (MODE == 4) outf[o] = res;
            else outb[o] = __float2bfloat16(res);
          }
        }
      }
    }
    return;
  }

#pragma unroll
  for (int mt = 0; mt < 4; ++mt) {
#pragma unroll
    for (int nt = 0; nt < 4; ++nt) {
      int n = n0 + wn + nt * 16 + l16;
      float bv = bias ? bias[n] : 0.f;
#pragma unroll
      for (int r = 0; r < 4; ++r) {
        int m = m0 + wm + mt * 16 + kq * 4 + r;
        float v = acc[mt][nt][r] + bv;
        size_t o = (size_t)m * N + n;
        if (MODE == 0) outf[o] = v;
        else if (MODE == 1) outb[o] = __float2bfloat16(v);
        else if (MODE == 2) outf[o] = addin[o] + gate[m] * v;
        else if (MODE == 3) outf[o] = sigm(v);
      }
    }
  }
}

// ---------------- router: hw = sigmoid(x @ rw + rb), N=12 ----------------
__global__ __launch_bounds__(256) void k_router(
    const float* __restrict__ x, const float* __restrict__ rw,
    const float* __restrict__ rb, float* __restrict__ hw) {
  __shared__ float row[HDIM];
  int tok = blockIdx.x, tid = threadIdx.x;
  for (int i = tid; i < HDIM; i += 256) row[i] = x[(size_t)tok * HDIM + i];
  __syncthreads();
  int wave = tid >> 6, lane = tid & 63;
  for (int o = wave; o < NHEADS; o += 4) {
    float a = 0.f;
    for (int k = lane; k < HDIM; k += 64) a += row[k] * rw[k * NHEADS + o];
    a = wred(a);
    if (lane == 0) hw[tok * NHEADS + o] = sigm(a + rb[o]);
  }
}

// ---------------- memory q/kg/v/g projections ----------------
__global__ __launch_bounds__(256) void k_qkvg(
    const float* __restrict__ xh, const float* __restrict__ Wq,
    const float* __restrict__ Wk, const float* __restrict__ Wv,
    const float* __restrict__ gw, const float* __restrict__ gb,
    float* __restrict__ q, float* __restrict__ kg, float* __restrict__ v,
    float* __restrict__ gout) {
  __shared__ float xm[NMEM * HEADD];
  __shared__ float gsh[NMEM];
  int tok = blockIdx.x, tid = threadIdx.x;
  for (int i = tid; i < NMEM * HEADD; i += 256)
    xm[i] = xh[(size_t)tok * HDIM + 6 * HEADD + i];
  __syncthreads();
  if (tid < NMEM) {
    float a = gb[tid];
    for (int d = 0; d < HEADD; ++d) a += xm[tid * HEADD + d] * gw[tid * HEADD + d];
    float s = sigm(a);
    gsh[tid] = s;
    gout[tok * NMEM + tid] = s;
  }
  __syncthreads();
  for (int i = tid; i < 1280; i += 256) {
    if (i < 384) {
      int n = i / HEADD, e = i % HEADD;
      const float* W = Wq + (size_t)n * HEADD * HEADD + e;
      const float* xr = xm + n * HEADD;
      float a = 0.f;
      for (int d = 0; d < HEADD; ++d) a += xr[d] * W[(size_t)d * HEADD];
      q[(size_t)tok * 384 + i] = a;
    } else if (i < 768) {
      int i2 = i - 384;
      int n = i2 / HEADD, e = i2 % HEADD;
      const float* W = Wk + (size_t)n * HEADD * HEADD + e;
      const float* xr = xm + n * HEADD;
      float a = 0.f;
      for (int d = 0; d < HEADD; ++d) a += xr[d] * W[(size_t)d * HEADD];
      kg[(size_t)tok * 384 + i2] = a * gsh[n];
    } else {
      int i2 = i - 768;
      int n = i2 / MEMD, e = i2 % MEMD;
      const float* W = Wv + (size_t)n * HEADD * MEMD + e;
      const float* xr = xm + n * HEADD;
      float a = 0.f;
      for (int d = 0; d < HEADD; ++d) a += xr[d] * W[(size_t)d * MEMD];
      v[(size_t)tok * 512 + i2] = a;
    }
  }
}

// ---------------- chunk means of g ----------------
__global__ __launch_bounds__(256) void k_gmean(const float* __restrict__ g,
                                               float* __restrict__ ga) {
  int idx = blockIdx.x * 256 + threadIdx.x;
  if (idx >= 512) return;
  int b = idx >> 7, ch = (idx >> 2) & 31, n = idx & 3;
  float s = 0.f;
  for (int t = 0; t < 64; ++t)
    s += g[((size_t)b * SEQ + ch * 64 + t) * NMEM + n];
  ga[idx] = s * (1.0f / 64.0f);
}

// ---------------- fast-weight memory scan ----------------
__global__ __launch_bounds__(256) void k_memscan(
    const float* __restrict__ q, const float* __restrict__ kg,
    const float* __restrict__ v, const float* __restrict__ ga,
    float* __restrict__ reads) {
  __shared__ float M[HEADD * 32];
  __shared__ float X[64 * HEADD];
  __shared__ float V[64 * 32];
  int bx = blockIdx.x;
  int b = bx >> 4, n = (bx >> 2) & 3, mc = bx & 3;
  int tid = threadIdx.x;
  for (int i = tid; i < HEADD * 32; i += 256) M[i] = 0.f;
  for (int ch = 0; ch < 32; ++ch) {
    __syncthreads();
    for (int i = tid; i < 64 * HEADD; i += 256) {
      int s = i / HEADD, d = i % HEADD;
      X[i] = q[((size_t)(b * SEQ + ch * 64 + s) * NMEM + n) * HEADD + d];
    }
    __syncthreads();
    {
      int m = tid & 31, s0 = (tid >> 5) * 8;
      for (int ss = 0; ss < 8; ++ss) {
        int s = s0 + ss;
        float a = 0.f;
        const float* xr = &X[s * HEADD];
        for (int d = 0; d < HEADD; ++d) a += xr[d] * M[d * 32 + m];
        reads[((size_t)(b * SEQ + ch * 64 + s) * NMEM + n) * MEMD + mc * 32 + m] = a;
      }
    }
    __syncthreads();
    for (int i = tid; i < 64 * HEADD; i += 256) {
      int s = i / HEADD, d = i % HEADD;
      X[i] = kg[((size_t)(b * SEQ + ch * 64 + s) * NMEM + n) * HEADD + d];
    }
    for (int i = tid; i < 64 * 32; i += 256) {
      int s = i >> 5, e = i & 31;
      V[i] = v[((size_t)(b * SEQ + ch * 64 + s) * NMEM + n) * MEMD + mc * 32 + e];
    }
    __syncthreads();
    float gav = ga[(b * 32 + ch) * NMEM + n];
    for (int i = tid; i < HEADD * 32; i += 256) {
      int d = i >> 5, m = i & 31;
      float wv = 0.f;
      for (int s = 0; s < 64; ++s) wv += X[s * HEADD + d] * V[s * 32 + m];
      M[i] = (1.f - gav) * M[i] + wv;
    }
  }
}

// ---------------- combine: out = (hconv + memproj) * head_weight ----------------
__global__ __launch_bounds__(256) void k_combine(
    const float* __restrict__ hconv, const float* __restrict__ reads,
    const float* __restrict__ Wout, const float* __restrict__ hw,
    float* __restrict__ outf, bf16* __restrict__ outb) {
  __shared__ float rd[NMEM * MEMD];
  int tok = blockIdx.x, tid = threadIdx.x;
  for (int i = tid; i < NMEM * MEMD; i += 256)
    rd[i] = reads[(size_t)tok * NMEM * MEMD + i];
  __syncthreads();
  for (int c = tid; c < HDIM; c += 256) {
    int head = c / HEADD, hd = c % HEADD;
    float v = hconv[(size_t)tok * HDIM + c];
    if (head >= 6 && head < 10) {
      int n = head - 6;
      const float* W = Wout + (size_t)(n * MEMD) * HEADD + hd;
      for (int m2 = 0; m2 < MEMD; ++m2) v += rd[n * MEMD + m2] * W[(size_t)m2 * HEADD];
    }
    v *= hw[tok * NHEADS + head];
    outf[(size_t)tok * HDIM + c] = v;
    outb[(size_t)tok * HDIM + c] = __float2bfloat16(v);
  }
}

// ---------------- elementwise helpers ----------------
__global__ __launch_bounds__(256) void k_f32bf16(const float* __restrict__ s,
                                                 bf16* __restrict__ d, size_t n) {
  size_t i = (size_t)blockIdx.x * 256 + threadIdx.x;
  if (i < n) d[i] = __float2bfloat16(s[i]);
}
__global__ __launch_bounds__(256) void k_mulb16(const float* __restrict__ a,
                                                const float* __restrict__ b,
                                                bf16* __restrict__ d, size_t n) {
  size_t i = (size_t)blockIdx.x * 256 + threadIdx.x;
  if (i < n) d[i] = __float2bfloat16(a[i] * b[i]);
}

extern "C" void kernel_launch(void* const* d_in, const int* in_sizes, int n_in,
                              void* d_out, int out_size, void* d_ws,
                              size_t ws_size, hipStream_t stream) {
  const float* x_in = (const float*)d_in[0];
  const float* norm1_w = (const float*)d_in[1];
  const float* norm2_w = (const float*)d_in[2];
  const float* norm3_w = (const float*)d_in[3];
  const float* cs_w = (const float*)d_in[4];
  const float* cs_b = (const float*)d_in[5];
  const float* cs_proj_w = (const float*)d_in[6];
  const float* cs_proj_b = (const float*)d_in[7];
  const float* gate_proj_w = (const float*)d_in[8];
  const float* router_w = (const float*)d_in[9];
  const float* router_b = (const float*)d_in[10];
  const float* head_w = (const float*)d_in[11];
  const float* head_b = (const float*)d_in[12];
  const float* mem_q = (const float*)d_in[13];
  const float* mem_k = (const float*)d_in[14];
  const float* mem_v = (const float*)d_in[15];
  const float* mem_gw = (const float*)d_in[16];
  const float* mem_gb = (const float*)d_in[17];
  const float* mem_out = (const float*)d_in[18];
  const float* mixgate_w = (const float*)d_in[19];
  const float* mixgate_b = (const float*)d_in[20];
  const float* mixing_w = (const float*)d_in[21];
  const float* mixing_b = (const float*)d_in[22];
  const float* ffn_in_w = (const float*)d_in[23];
  const float* ffn_out_w = (const float*)d_in[24];
  const float* cg_w = (const float*)d_in[25];
  const float* cg_b = (const float*)d_in[26];
  const float* sg_w = (const float*)d_in[27];
  const float* sg_b = (const float*)d_in[28];
  const float* fg_w = (const float*)d_in[29];
  const float* fg_b = (const float*)d_in[30];
  float* out = (float*)d_out;

  // ---- manual arena (~222 MB peak; honors ws_size budget) ----
  char* wsp = (char*)d_ws;
  size_t off = 0;
  auto alloc = [&](size_t bytes) -> char* {
    char* p = wsp + off;
    off += (bytes + 255) & ~(size_t)255;
    return p;
  };
  bf16* NB = (bf16*)alloc((size_t)TOKENS * HDIM * 2);     // 18.9 MB
  float* F1 = (float*)alloc((size_t)TOKENS * HDIM * 4);   // 37.7 MB
  float* F2 = (float*)alloc((size_t)TOKENS * HDIM * 4);   // 37.7 MB
  float* F3 = (float*)alloc((size_t)TOKENS * HDIM * 4);   // 37.7 MB
  char* REG = alloc((size_t)TOKENS * FINNER * 2);         // 75.5 MB shared
  // stage-B view of REG:
  float* qb = (float*)REG;
  float* kgb = (float*)(REG + (size_t)TOKENS * 384 * 4);
  float* vb = (float*)((char*)kgb + (size_t)TOKENS * 384 * 4);
  float* rdb = (float*)((char*)vb + (size_t)TOKENS * 512 * 4);
  // stage-C view of REG:
  bf16* XG = (bf16*)REG;  // [8192, 4608] bf16
  bf16* WTcs = (bf16*)alloc((size_t)1152 * 1152 * 2);
  bf16* WTgp = (bf16*)alloc((size_t)2304 * 1152 * 2);
  bf16* WTmg = (bf16*)alloc((size_t)1152 * 1152 * 2);
  bf16* WTmx = (bf16*)alloc((size_t)1152 * 1152 * 2);
  float* G1 = (float*)alloc(TOKENS * 4);
  float* G2 = (float*)alloc(TOKENS * 4);
  float* G3 = (float*)alloc(TOKENS * 4);
  float* GM = (float*)alloc((size_t)TOKENS * NMEM * 4);
  float* GA = (float*)alloc(4 * 32 * NMEM * 4);
  float* HW = (float*)alloc((size_t)TOKENS * NHEADS * 4);
  // stage-C weights live in F1/F2 (free by then):
  bf16* WTfin = (bf16*)F1;   // [9216,1152] bf16 = 21.2 MB <= 37.7
  bf16* WTfout = (bf16*)F2;  // [1152,4608] bf16 = 10.6 MB <= 37.7

  const int gE = (TOKENS * HDIM) / 256;  // 36864

  // small-weight prep
  k_transpose_bf16<<<dim3(36, 36), 256, 0, stream>>>(cs_proj_w, WTcs, 1152, 1152);
  k_transpose_pair<<<dim3(72, 36), 256, 0, stream>>>(gate_proj_w, WTgp, 1152, 2304);
  k_transpose_bf16<<<dim3(36, 36), 256, 0, stream>>>(mixgate_w, WTmg, 1152, 1152);
  k_transpose_bf16<<<dim3(36, 36), 256, 0, stream>>>(mixing_w, WTmx, 1152, 1152);

  // ---- stage A: conv stack ----
  k_rms_gate<<<TOKENS, 256, 0, stream>>>(x_in, norm1_w, cg_w, cg_b, NB, F1, G1, 1);
  {
    int dil[6] = {1, 2, 4, 8, 16, 32};
    const float* src = F1;
    float* dst = F2;
    for (int i = 0; i < 6; ++i) {
      k_dconv_gelu<<<gE, 256, 0, stream>>>(src, dst, cs_w + (size_t)i * HDIM * 4,
                                           cs_b + (size_t)i * HDIM, dil[i]);
      const float* tmp = dst;
      dst = (float*)src;
      src = tmp;
    }
    k_f32bf16<<<gE, 256, 0, stream>>>(src, NB, (size_t)TOKENS * HDIM);  // src==F1
  }
  k_gemm<2><<<dim3(9, 64), 256, 0, stream>>>(NB, WTcs, cs_proj_b, G1, x_in, out,
                                             nullptr, TOKENS, 1152, 1152);

  // ---- stage B: multi-head state ----
  k_rms_gate<<<TOKENS, 256, 0, stream>>>(out, norm2_w, sg_w, sg_b, NB, F1, G2, 1);
  k_router<<<TOKENS, 256, 0, stream>>>(F1, router_w, router_b, HW);
  // fused gate_proj + swish: xh -> F3
  k_gemm<4><<<dim3(18, 64), 256, 0, stream>>>(NB, WTgp, nullptr, nullptr, nullptr,
                                              F3, nullptr, TOKENS, 2304, 1152);
  k_headconv<<<gE, 256, 0, stream>>>(F3, F1, head_w, head_b, 0);
  k_headconv<<<gE, 256, 0, stream>>>(F1, F2, head_w, head_b, 1);
  k_headconv<<<gE, 256, 0, stream>>>(F2, F1, head_w, head_b, 2);
  k_qkvg<<<TOKENS, 256, 0, stream>>>(F3, mem_q, mem_k, mem_v, mem_gw, mem_gb,
                                     qb, kgb, vb, GM);
  k_gmean<<<2, 256, 0, stream>>>(GM, GA);
  k_memscan<<<64, 256, 0, stream>>>(qb, kgb, vb, GA, rdb);
  k_combine<<<TOKENS, 256, 0, stream>>>(F1, rdb, mem_out, HW, F2, NB);
  k_gemm<3><<<dim3(9, 64), 256, 0, stream>>>(NB, WTmg, mixgate_b, nullptr, nullptr,
                                             F3, nullptr, TOKENS, 1152, 1152);
  k_mulb16<<<gE, 256, 0, stream>>>(F2, F3, NB, (size_t)TOKENS * HDIM);
  k_gemm<2><<<dim3(9, 64), 256, 0, stream>>>(NB, WTmx, mixing_b, G2, out, out,
                                             nullptr, TOKENS, 1152, 1152);

  // ---- stage C: GLU FFN ----
  k_rms_gate<<<TOKENS, 256, 0, stream>>>(out, norm3_w, fg_w, fg_b, NB, nullptr, G3, 0);
  k_transpose_pair<<<dim3(288, 36), 256, 0, stream>>>(ffn_in_w, WTfin, 1152, 9216);
  k_transpose_bf16<<<dim3(36, 144), 256, 0, stream>>>(ffn_out_w, WTfout, 4608, 1152);
  // fused ffn_in + GLU: -> XG bf16
  k_gemm<5><<<dim3(72, 64), 256, 0, stream>>>(NB, WTfin, nullptr, nullptr, nullptr,
                                              nullptr, XG, TOKENS, 9216, 1152);
  k_gemm<2><<<dim3(9, 64), 256, 0, stream>>>(XG, WTfout, nullptr, G3, out, out,
                                             nullptr, TOKENS, 1152, 4608);
}

// Round 3
// 1799.167 us; speedup vs baseline: 1.4362x; 1.4362x over previous
//
#include <hip/hip_runtime.h>
#include <hip/hip_bf16.h>
#include <math.h>

#define TOKENS 8192
#define HDIM 1152
#define SEQ 2048
#define NHEADS 12
#define HEADD 96
#define NMEM 4
#define MEMD 128
#define FINNER 4608

typedef __hip_bfloat16 bf16;
typedef __attribute__((ext_vector_type(8))) short short8;
typedef __attribute__((ext_vector_type(4))) float floatx4;

__device__ __constant__ int g_hd_dil[NHEADS * 3] = {
    1, 2, 4,   1, 1, 1,    4, 8, 16,   8, 16, 32,
    32, 64, 128, 64, 128, 256, 256, 512, 1024, 1, 100, 200,
    1, 500, 1000, 1, 1024, 2048, 3, 9, 27, 5, 25, 125};

__device__ inline float sigm(float x) { return 1.0f / (1.0f + expf(-x)); }
__device__ inline float gelu_exact(float x) {
  return 0.5f * x * (1.0f + erff(x * 0.70710678118654752f));
}
__device__ inline float wred(float v) {
#pragma unroll
  for (int o = 32; o > 0; o >>= 1) v += __shfl_down(v, o);
  return v;
}

// ---------------- transpose f32 [K,N] -> bf16 [N,K] ----------------
__global__ __launch_bounds__(256) void k_transpose_bf16(
    const float* __restrict__ W, bf16* __restrict__ WT, int K, int N) {
  __shared__ float t[32][33];
  int k0 = blockIdx.y * 32, n0 = blockIdx.x * 32;
  int tx = threadIdx.x & 31, ty = threadIdx.x >> 5;  // ty 0..7
#pragma unroll
  for (int i = 0; i < 32; i += 8)
    t[ty + i][tx] = W[(size_t)(k0 + ty + i) * N + (n0 + tx)];
  __syncthreads();
#pragma unroll
  for (int i = 0; i < 32; i += 8)
    WT[(size_t)(n0 + ty + i) * K + (k0 + tx)] = __float2bfloat16(t[tx][ty + i]);
}

// ---- pair-permuted transpose: out row 2c = W[:,c], row 2c+1 = W[:,half+c] ----
__global__ __launch_bounds__(256) void k_transpose_pair(
    const float* __restrict__ W, bf16* __restrict__ WT, int K, int N) {
  __shared__ float t[32][33];
  int half = N >> 1;
  int k0 = blockIdx.y * 32, n0 = blockIdx.x * 32;
  int tx = threadIdx.x & 31, ty = threadIdx.x >> 5;
  int c = (tx < 16) ? (n0 / 2 + tx) : (half + n0 / 2 + tx - 16);
#pragma unroll
  for (int i = 0; i < 32; i += 8)
    t[ty + i][tx] = W[(size_t)(k0 + ty + i) * N + c];
  __syncthreads();
#pragma unroll
  for (int i = 0; i < 32; i += 8) {
    int r = ty + i;
    int cc = (r >> 1) + (r & 1) * 16;
    WT[(size_t)(n0 + r) * K + (k0 + tx)] = __float2bfloat16(t[tx][cc]);
  }
}

// ---------------- rmsnorm + scalar gate ----------------
__global__ __launch_bounds__(256) void k_rms_gate(
    const float* __restrict__ x, const float* __restrict__ nw,
    const float* __restrict__ gw, const float* __restrict__ gb,
    bf16* __restrict__ outb, float* outf, float* __restrict__ gout,
    int writef) {
  __shared__ float r1[4], r2[4];
  int tok = blockIdx.x;
  int tid = threadIdx.x;
  const float* row = x + (size_t)tok * HDIM;
  float s2 = 0.f, gd = 0.f;
  for (int i = tid; i < HDIM; i += 256) {
    float a = row[i];
    s2 += a * a;
    gd += a * gw[i];
  }
  s2 = wred(s2);
  gd = wred(gd);
  int wave = tid >> 6, lane = tid & 63;
  if (lane == 0) {
    r1[wave] = s2;
    r2[wave] = gd;
  }
  __syncthreads();
  s2 = r1[0] + r1[1] + r1[2] + r1[3];
  gd = r2[0] + r2[1] + r2[2] + r2[3];
  float rn = 1.0f / sqrtf(s2 / (float)HDIM + 1e-6f);
  if (tid == 0) gout[tok] = sigm(gd + gb[0]);
  for (int i = tid; i < HDIM; i += 256) {
    float a = row[i] * rn * nw[i];
    outb[(size_t)tok * HDIM + i] = __float2bfloat16(a);
    if (writef) outf[(size_t)tok * HDIM + i] = a;
  }
}

// ---------------- fused conv stack: 6 dilated stages in LDS ----------------
// block = (batch, 256-token tile, 32-ch slice); halo 189 tokens; dbl-buffered.
#define CS_T 256
#define CS_HALO 189
#define CS_ROWS 445
__global__ __launch_bounds__(256) void k_convstack(
    const float* __restrict__ hin, bf16* __restrict__ outb,
    const float* __restrict__ cw, const float* __restrict__ cb) {
  extern __shared__ float lds[];
  float* cur = lds;
  float* nxt = lds + CS_ROWS * 32;
  int bx = blockIdx.x;
  int cs = bx % 36;
  int tile = (bx / 36) & 7;
  int b = bx / 288;
  int c0 = cs * 32;
  int S0 = tile * CS_T;
  int tid = threadIdx.x;
  int c = tid & 31;
  // stage input
  for (int i = tid; i < CS_ROWS * 32; i += 256) {
    int p = i >> 5, cc = i & 31;
    int sg = S0 - CS_HALO + p;
    cur[i] = (sg >= 0)
                 ? hin[((size_t)(b * SEQ + sg)) * HDIM + c0 + cc]
                 : 0.f;
  }
  const int dil[6] = {1, 2, 4, 8, 16, 32};
  const int Nk[6] = {3, 9, 21, 45, 93, 189};
#pragma unroll
  for (int k = 0; k < 6; ++k) {
    int d = dil[k];
    float w0 = cw[((size_t)k * HDIM + c0 + c) * 4 + 0];
    float w1 = cw[((size_t)k * HDIM + c0 + c) * 4 + 1];
    float w2 = cw[((size_t)k * HDIM + c0 + c) * 4 + 2];
    float w3 = cw[((size_t)k * HDIM + c0 + c) * 4 + 3];
    float bb = cb[(size_t)k * HDIM + c0 + c];
    __syncthreads();
    for (int p = Nk[k] + (tid >> 5); p < CS_ROWS; p += 8) {
      int i = p * 32 + c;
      int sg = S0 - CS_HALO + p;
      float acc = bb + w0 * cur[i - 3 * d * 32] + w1 * cur[i - 2 * d * 32] +
                  w2 * cur[i - d * 32] + w3 * cur[i];
      nxt[i] = (sg >= 0) ? (cur[i] + gelu_exact(acc)) : 0.f;
    }
    float* t = cur;
    cur = nxt;
    nxt = t;
  }
  __syncthreads();
  for (int r = tid >> 5; r < CS_T; r += 8) {
    outb[((size_t)(b * SEQ + S0 + r)) * HDIM + c0 + c] =
        __float2bfloat16(cur[(CS_HALO + r) * 32 + c]);
  }
}

// ---------------- per-head conv step j: h = h + dconv(h) ----------------
__global__ __launch_bounds__(256) void k_headconv(
    const float* __restrict__ hin, float* __restrict__ hout,
    const float* __restrict__ hw_, const float* __restrict__ hb_, int j) {
  size_t idx = (size_t)blockIdx.x * 256 + threadIdx.x;
  if (idx >= (size_t)TOKENS * HDIM) return;
  int c = (int)(idx % HDIM);
  int head = c / HEADD, hd = c % HEADD;
  size_t tok = idx / HDIM;
  int s = (int)(tok % SEQ);
  int d = g_hd_dil[head * 3 + j];
  const float* w = hw_ + ((size_t)(head * 3 + j) * HEADD + hd) * 4;
  float acc = hb_[(head * 3 + j) * HEADD + hd];
#pragma unroll
  for (int jj = 0; jj < 4; ++jj) {
    int back = (3 - jj) * d;
    if (s - back >= 0) acc += w[jj] * hin[idx - (size_t)back * HDIM];
  }
  hout[idx] = hin[idx] + acc;
}

// ---------------- GEMM: C[M,N] = A[M,K](bf16) * BT[N,K](bf16)^T ----------------
// MODE 0: store f32            MODE 1: store bf16
// MODE 2: out = addin + gate[m]*(acc+bias)    MODE 3: sigmoid -> f32
// MODE 4: pair-GLU (even col a, odd col g) -> a*sigm(g) f32, N halves
// MODE 5: pair-GLU -> bf16
template <int MODE>
__global__ __launch_bounds__(256) void k_gemm(
    const bf16* __restrict__ A, const bf16* __restrict__ BT,
    const float* __restrict__ bias, const float* __restrict__ gate,
    const float* addin, float* outf, bf16* outb, int M, int N, int K) {
  __shared__ bf16 As[128 * 40];
  __shared__ bf16 Bs[128 * 40];
  const int tid = threadIdx.x;
  const int m0 = blockIdx.y * 128, n0 = blockIdx.x * 128;
  const int wave = tid >> 6, lane = tid & 63;
  const int wm = (wave & 1) * 64, wn = (wave >> 1) * 64;
  const int l16 = lane & 15, kq = lane >> 4;
  const int srow = tid >> 2, schunk = (tid & 3) * 8;
  floatx4 acc[4][4];
  floatx4 zero = {0.f, 0.f, 0.f, 0.f};
#pragma unroll
  for (int i = 0; i < 4; ++i)
#pragma unroll
    for (int jj = 0; jj < 4; ++jj) acc[i][jj] = zero;

  for (int k0 = 0; k0 < K; k0 += 32) {
    __syncthreads();
#pragma unroll
    for (int h = 0; h < 2; ++h) {
      int r = srow + h * 64;
      *reinterpret_cast<int4*>(&As[r * 40 + schunk]) =
          *reinterpret_cast<const int4*>(&A[(size_t)(m0 + r) * K + k0 + schunk]);
      *reinterpret_cast<int4*>(&Bs[r * 40 + schunk]) =
          *reinterpret_cast<const int4*>(&BT[(size_t)(n0 + r) * K + k0 + schunk]);
    }
    __syncthreads();
    short8 af[4], bfr[4];
#pragma unroll
    for (int t = 0; t < 4; ++t) {
      af[t] = *reinterpret_cast<const short8*>(&As[(wm + t * 16 + l16) * 40 + kq * 8]);
      bfr[t] = *reinterpret_cast<const short8*>(&Bs[(wn + t * 16 + l16) * 40 + kq * 8]);
    }
#pragma unroll
    for (int mt = 0; mt < 4; ++mt)
#pragma unroll
      for (int nt = 0; nt < 4; ++nt)
        acc[mt][nt] = __builtin_amdgcn_mfma_f32_16x16x32_bf16(
            af[mt], bfr[nt], acc[mt][nt], 0, 0, 0);
  }

  if (MODE == 4 || MODE == 5) {
    const int halfN = N >> 1;
#pragma unroll
    for (int mt = 0; mt < 4; ++mt) {
#pragma unroll
      for (int nt = 0; nt < 4; ++nt) {
        int nn = n0 + wn + nt * 16 + l16;
#pragma unroll
        for (int r = 0; r < 4; ++r) {
          float v = acc[mt][nt][r];
          float g = __shfl_xor(v, 1);
          if ((lane & 1) == 0) {
            int m = m0 + wm + mt * 16 + kq * 4 + r;
            float res = v * sigm(g);
            size_t o = (size_t)m * halfN + (nn >> 1);
            if (MODE == 4) outf[o] = res;
            else outb[o] = __float2bfloat16(res);
          }
        }
      }
    }
    return;
  }

#pragma unroll
  for (int mt = 0; mt < 4; ++mt) {
#pragma unroll
    for (int nt = 0; nt < 4; ++nt) {
      int n = n0 + wn + nt * 16 + l16;
      float bv = bias ? bias[n] : 0.f;
#pragma unroll
      for (int r = 0; r < 4; ++r) {
        int m = m0 + wm + mt * 16 + kq * 4 + r;
        float v = acc[mt][nt][r] + bv;
        size_t o = (size_t)m * N + n;
        if (MODE == 0) outf[o] = v;
        else if (MODE == 1) outb[o] = __float2bfloat16(v);
        else if (MODE == 2) outf[o] = addin[o] + gate[m] * v;
        else if (MODE == 3) outf[o] = sigm(v);
      }
    }
  }
}

// ---------------- router: hw = sigmoid(x @ rw + rb), N=12 ----------------
__global__ __launch_bounds__(256) void k_router(
    const float* __restrict__ x, const float* __restrict__ rw,
    const float* __restrict__ rb, float* __restrict__ hw) {
  __shared__ float row[HDIM];
  int tok = blockIdx.x, tid = threadIdx.x;
  for (int i = tid; i < HDIM; i += 256) row[i] = x[(size_t)tok * HDIM + i];
  __syncthreads();
  int wave = tid >> 6, lane = tid & 63;
  for (int o = wave; o < NHEADS; o += 4) {
    float a = 0.f;
    for (int k = lane; k < HDIM; k += 64) a += row[k] * rw[k * NHEADS + o];
    a = wred(a);
    if (lane == 0) hw[tok * NHEADS + o] = sigm(a + rb[o]);
  }
}

// ---------------- memory q/kg/v/g projections ----------------
__global__ __launch_bounds__(256) void k_qkvg(
    const float* __restrict__ xh, const float* __restrict__ Wq,
    const float* __restrict__ Wk, const float* __restrict__ Wv,
    const float* __restrict__ gw, const float* __restrict__ gb,
    float* __restrict__ q, float* __restrict__ kg, float* __restrict__ v,
    float* __restrict__ gout) {
  __shared__ float xm[NMEM * HEADD];
  __shared__ float gsh[NMEM];
  int tok = blockIdx.x, tid = threadIdx.x;
  for (int i = tid; i < NMEM * HEADD; i += 256)
    xm[i] = xh[(size_t)tok * HDIM + 6 * HEADD + i];
  __syncthreads();
  if (tid < NMEM) {
    float a = gb[tid];
    for (int d = 0; d < HEADD; ++d) a += xm[tid * HEADD + d] * gw[tid * HEADD + d];
    float s = sigm(a);
    gsh[tid] = s;
    gout[tok * NMEM + tid] = s;
  }
  __syncthreads();
  for (int i = tid; i < 1280; i += 256) {
    if (i < 384) {
      int n = i / HEADD, e = i % HEADD;
      const float* W = Wq + (size_t)n * HEADD * HEADD + e;
      const float* xr = xm + n * HEADD;
      float a = 0.f;
      for (int d = 0; d < HEADD; ++d) a += xr[d] * W[(size_t)d * HEADD];
      q[(size_t)tok * 384 + i] = a;
    } else if (i < 768) {
      int i2 = i - 384;
      int n = i2 / HEADD, e = i2 % HEADD;
      const float* W = Wk + (size_t)n * HEADD * HEADD + e;
      const float* xr = xm + n * HEADD;
      float a = 0.f;
      for (int d = 0; d < HEADD; ++d) a += xr[d] * W[(size_t)d * HEADD];
      kg[(size_t)tok * 384 + i2] = a * gsh[n];
    } else {
      int i2 = i - 768;
      int n = i2 / MEMD, e = i2 % MEMD;
      const float* W = Wv + (size_t)n * HEADD * MEMD + e;
      const float* xr = xm + n * HEADD;
      float a = 0.f;
      for (int d = 0; d < HEADD; ++d) a += xr[d] * W[(size_t)d * MEMD];
      v[(size_t)tok * 512 + i2] = a;
    }
  }
}

// ---------------- chunk means of g ----------------
__global__ __launch_bounds__(256) void k_gmean(const float* __restrict__ g,
                                               float* __restrict__ ga) {
  int idx = blockIdx.x * 256 + threadIdx.x;
  if (idx >= 512) return;
  int b = idx >> 7, ch = (idx >> 2) & 31, n = idx & 3;
  float s = 0.f;
  for (int t = 0; t < 64; ++t)
    s += g[((size_t)b * SEQ + ch * 64 + t) * NMEM + n];
  ga[idx] = s * (1.0f / 64.0f);
}

// ---------------- pass 1: per-chunk writes W[bnc][96][128] ----------------
__global__ __launch_bounds__(256) void k_memW(const float* __restrict__ kg,
                                              const float* __restrict__ v,
                                              float* __restrict__ W) {
  __shared__ float X[64 * 96];
  __shared__ float V[64 * 128];
  int bx = blockIdx.x;
  int bn = bx >> 5, ch = bx & 31;
  int b = bn >> 2, n = bn & 3;
  int t0 = b * SEQ + ch * 64;
  int tid = threadIdx.x;
  for (int i = tid; i < 64 * 96; i += 256) {
    int s = i / 96, d = i % 96;
    X[i] = kg[((size_t)(t0 + s) * NMEM + n) * HEADD + d];
  }
  for (int i = tid; i < 64 * 128; i += 256) {
    int s = i >> 7, m = i & 127;
    V[i] = v[((size_t)(t0 + s) * NMEM + n) * MEMD + m];
  }
  __syncthreads();
  float* Wb = W + (size_t)bx * 96 * 128;
  for (int t = tid; t < 768; t += 256) {
    int d0 = (t >> 5) * 4, m0 = (t & 31) * 4;
    float acc[4][4] = {};
    for (int s = 0; s < 64; ++s) {
      float4 xv = *reinterpret_cast<const float4*>(&X[s * 96 + d0]);
      float4 vv = *reinterpret_cast<const float4*>(&V[s * 128 + m0]);
      float xa[4] = {xv.x, xv.y, xv.z, xv.w};
      float va[4] = {vv.x, vv.y, vv.z, vv.w};
#pragma unroll
      for (int a = 0; a < 4; ++a)
#pragma unroll
        for (int e = 0; e < 4; ++e) acc[a][e] += xa[a] * va[e];
    }
#pragma unroll
    for (int a = 0; a < 4; ++a) {
      float4 o = {acc[a][0], acc[a][1], acc[a][2], acc[a][3]};
      *reinterpret_cast<float4*>(&Wb[(size_t)(d0 + a) * 128 + m0]) = o;
    }
  }
}

// ---------------- pass 2: prefix scan over chunks ----------------
__global__ __launch_bounds__(256) void k_memscanM(const float* __restrict__ W,
                                                  const float* __restrict__ ga,
                                                  float* __restrict__ Mp) {
  int bx = blockIdx.x;
  int bn = bx / 48, j = bx % 48;
  int elem = j * 256 + threadIdx.x;
  int b = bn >> 2, n = bn & 3;
  float M = 0.f;
  for (int ch = 0; ch < 32; ++ch) {
    size_t base = ((size_t)bn * 32 + ch) * 12288 + elem;
    Mp[base] = M;
    float g = ga[(b * 32 + ch) * NMEM + n];
    M = (1.f - g) * M + W[base];
  }
}

// ---------------- pass 3: reads = q @ M_prefix ----------------
__global__ __launch_bounds__(256) void k_memR(const float* __restrict__ q,
                                              const float* __restrict__ Mp,
                                              float* __restrict__ rd) {
  extern __shared__ float smem[];
  float* Q = smem;            // 64*96
  float* Ms = smem + 64 * 96; // 96*128
  int bx = blockIdx.x;
  int bn = bx >> 5, ch = bx & 31;
  int b = bn >> 2, n = bn & 3;
  int t0 = b * SEQ + ch * 64;
  int tid = threadIdx.x;
  for (int i = tid; i < 64 * 96; i += 256) {
    int s = i / 96, d = i % 96;
    Q[i] = q[((size_t)(t0 + s) * NMEM + n) * HEADD + d];
  }
  for (int i = tid; i < 96 * 128; i += 256)
    Ms[i] = Mp[((size_t)bn * 32 + ch) * 12288 + i];
  __syncthreads();
  for (int t = tid; t < 512; t += 256) {
    int s0 = (t >> 5) * 4, m0 = (t & 31) * 4;
    float acc[4][4] = {};
    for (int k = 0; k < 96; ++k) {
      float4 mv = *reinterpret_cast<const float4*>(&Ms[k * 128 + m0]);
      float ma[4] = {mv.x, mv.y, mv.z, mv.w};
#pragma unroll
      for (int si = 0; si < 4; ++si) {
        float qs = Q[(s0 + si) * 96 + k];
#pragma unroll
        for (int mi = 0; mi < 4; ++mi) acc[si][mi] += qs * ma[mi];
      }
    }
#pragma unroll
    for (int si = 0; si < 4; ++si) {
      float4 o = {acc[si][0], acc[si][1], acc[si][2], acc[si][3]};
      *reinterpret_cast<float4*>(
          &rd[((size_t)(t0 + s0 + si) * NMEM + n) * MEMD + m0]) = o;
    }
  }
}

// ---------------- combine: out = (hconv + memproj) * head_weight ----------------
__global__ __launch_bounds__(256) void k_combine(
    const float* __restrict__ hconv, const float* __restrict__ reads,
    const float* __restrict__ Wout, const float* __restrict__ hw,
    float* __restrict__ outf, bf16* __restrict__ outb) {
  __shared__ float rd[NMEM * MEMD];
  int tok = blockIdx.x, tid = threadIdx.x;
  for (int i = tid; i < NMEM * MEMD; i += 256)
    rd[i] = reads[(size_t)tok * NMEM * MEMD + i];
  __syncthreads();
  for (int c = tid; c < HDIM; c += 256) {
    int head = c / HEADD, hd = c % HEADD;
    float v = hconv[(size_t)tok * HDIM + c];
    if (head >= 6 && head < 10) {
      int n = head - 6;
      const float* W = Wout + (size_t)(n * MEMD) * HEADD + hd;
      for (int m2 = 0; m2 < MEMD; ++m2) v += rd[n * MEMD + m2] * W[(size_t)m2 * HEADD];
    }
    v *= hw[tok * NHEADS + head];
    outf[(size_t)tok * HDIM + c] = v;
    outb[(size_t)tok * HDIM + c] = __float2bfloat16(v);
  }
}

// ---------------- elementwise helper ----------------
__global__ __launch_bounds__(256) void k_mulb16(const float* __restrict__ a,
                                                const float* __restrict__ b,
                                                bf16* __restrict__ d, size_t n) {
  size_t i = (size_t)blockIdx.x * 256 + threadIdx.x;
  if (i < n) d[i] = __float2bfloat16(a[i] * b[i]);
}

extern "C" void kernel_launch(void* const* d_in, const int* in_sizes, int n_in,
                              void* d_out, int out_size, void* d_ws,
                              size_t ws_size, hipStream_t stream) {
  const float* x_in = (const float*)d_in[0];
  const float* norm1_w = (const float*)d_in[1];
  const float* norm2_w = (const float*)d_in[2];
  const float* norm3_w = (const float*)d_in[3];
  const float* cs_w = (const float*)d_in[4];
  const float* cs_b = (const float*)d_in[5];
  const float* cs_proj_w = (const float*)d_in[6];
  const float* cs_proj_b = (const float*)d_in[7];
  const float* gate_proj_w = (const float*)d_in[8];
  const float* router_w = (const float*)d_in[9];
  const float* router_b = (const float*)d_in[10];
  const float* head_w = (const float*)d_in[11];
  const float* head_b = (const float*)d_in[12];
  const float* mem_q = (const float*)d_in[13];
  const float* mem_k = (const float*)d_in[14];
  const float* mem_v = (const float*)d_in[15];
  const float* mem_gw = (const float*)d_in[16];
  const float* mem_gb = (const float*)d_in[17];
  const float* mem_out = (const float*)d_in[18];
  const float* mixgate_w = (const float*)d_in[19];
  const float* mixgate_b = (const float*)d_in[20];
  const float* mixing_w = (const float*)d_in[21];
  const float* mixing_b = (const float*)d_in[22];
  const float* ffn_in_w = (const float*)d_in[23];
  const float* ffn_out_w = (const float*)d_in[24];
  const float* cg_w = (const float*)d_in[25];
  const float* cg_b = (const float*)d_in[26];
  const float* sg_w = (const float*)d_in[27];
  const float* sg_b = (const float*)d_in[28];
  const float* fg_w = (const float*)d_in[29];
  const float* fg_b = (const float*)d_in[30];
  float* out = (float*)d_out;

  char* wsp = (char*)d_ws;
  size_t off = 0;
  auto alloc = [&](size_t bytes) -> char* {
    char* p = wsp + off;
    off += (bytes + 255) & ~(size_t)255;
    return p;
  };
  bf16* NB = (bf16*)alloc((size_t)TOKENS * HDIM * 2);     // 18.9 MB
  float* F1 = (float*)alloc((size_t)TOKENS * HDIM * 4);   // 37.7 MB
  float* F2 = (float*)alloc((size_t)TOKENS * HDIM * 4);   // 37.7 MB
  float* F3 = (float*)alloc((size_t)TOKENS * HDIM * 4);   // 37.7 MB
  char* REG = alloc((size_t)TOKENS * FINNER * 2);         // 75.5 MB shared
  float* qb = (float*)REG;
  float* kgb = (float*)(REG + (size_t)TOKENS * 384 * 4);
  float* vb = (float*)((char*)kgb + (size_t)TOKENS * 384 * 4);
  float* rdb = (float*)((char*)vb + (size_t)TOKENS * 512 * 4);
  bf16* XG = (bf16*)REG;  // stage-C view
  bf16* WTcs = (bf16*)alloc((size_t)1152 * 1152 * 2);
  bf16* WTgp = (bf16*)alloc((size_t)2304 * 1152 * 2);
  bf16* WTmg = (bf16*)alloc((size_t)1152 * 1152 * 2);
  bf16* WTmx = (bf16*)alloc((size_t)1152 * 1152 * 2);
  float* G1 = (float*)alloc(TOKENS * 4);
  float* G2 = (float*)alloc(TOKENS * 4);
  float* G3 = (float*)alloc(TOKENS * 4);
  float* GM = (float*)alloc((size_t)TOKENS * NMEM * 4);
  float* GA = (float*)alloc(4 * 32 * NMEM * 4);
  float* HW = (float*)alloc((size_t)TOKENS * NHEADS * 4);
  // stage-C weights in F1/F2 (free by then)
  bf16* WTfin = (bf16*)F1;
  bf16* WTfout = (bf16*)F2;
  // memory-scan scratch in F2/F3 (dead during the scan)
  float* Wbuf = F2;   // 25.2 MB
  float* Mpref = F3;  // 25.2 MB

  const int gE = (TOKENS * HDIM) / 256;

  k_transpose_bf16<<<dim3(36, 36), 256, 0, stream>>>(cs_proj_w, WTcs, 1152, 1152);
  k_transpose_pair<<<dim3(72, 36), 256, 0, stream>>>(gate_proj_w, WTgp, 1152, 2304);
  k_transpose_bf16<<<dim3(36, 36), 256, 0, stream>>>(mixgate_w, WTmg, 1152, 1152);
  k_transpose_bf16<<<dim3(36, 36), 256, 0, stream>>>(mixing_w, WTmx, 1152, 1152);

  // ---- stage A: fused conv stack ----
  k_rms_gate<<<TOKENS, 256, 0, stream>>>(x_in, norm1_w, cg_w, cg_b, NB, F1, G1, 1);
  k_convstack<<<1152, 256, 2 * CS_ROWS * 32 * 4, stream>>>(F1, NB, cs_w, cs_b);
  k_gemm<2><<<dim3(9, 64), 256, 0, stream>>>(NB, WTcs, cs_proj_b, G1, x_in, out,
                                             nullptr, TOKENS, 1152, 1152);

  // ---- stage B: multi-head state ----
  k_rms_gate<<<TOKENS, 256, 0, stream>>>(out, norm2_w, sg_w, sg_b, NB, F1, G2, 1);
  k_router<<<TOKENS, 256, 0, stream>>>(F1, router_w, router_b, HW);
  k_gemm<4><<<dim3(18, 64), 256, 0, stream>>>(NB, WTgp, nullptr, nullptr, nullptr,
                                              F3, nullptr, TOKENS, 2304, 1152);
  k_headconv<<<gE, 256, 0, stream>>>(F3, F1, head_w, head_b, 0);
  k_headconv<<<gE, 256, 0, stream>>>(F1, F2, head_w, head_b, 1);
  k_headconv<<<gE, 256, 0, stream>>>(F2, F1, head_w, head_b, 2);
  k_qkvg<<<TOKENS, 256, 0, stream>>>(F3, mem_q, mem_k, mem_v, mem_gw, mem_gb,
                                     qb, kgb, vb, GM);
  k_gmean<<<2, 256, 0, stream>>>(GM, GA);
  k_memW<<<512, 256, 0, stream>>>(kgb, vb, Wbuf);
  k_memscanM<<<768, 256, 0, stream>>>(Wbuf, GA, Mpref);
  k_memR<<<512, 256, (64 * 96 + 96 * 128) * 4, stream>>>(qb, Mpref, rdb);
  k_combine<<<TOKENS, 256, 0, stream>>>(F1, rdb, mem_out, HW, F2, NB);
  k_gemm<3><<<dim3(9, 64), 256, 0, stream>>>(NB, WTmg, mixgate_b, nullptr, nullptr,
                                             F3, nullptr, TOKENS, 1152, 1152);
  k_mulb16<<<gE, 256, 0, stream>>>(F2, F3, NB, (size_t)TOKENS * HDIM);
  k_gemm<2><<<dim3(9, 64), 256, 0, stream>>>(NB, WTmx, mixing_b, G2, out, out,
                                             nullptr, TOKENS, 1152, 1152);

  // ---- stage C: GLU FFN ----
  k_rms_gate<<<TOKENS, 256, 0, stream>>>(out, norm3_w, fg_w, fg_b, NB, nullptr, G3, 0);
  k_transpose_pair<<<dim3(288, 36), 256, 0, stream>>>(ffn_in_w, WTfin, 1152, 9216);
  k_transpose_bf16<<<dim3(36, 144), 256, 0, stream>>>(ffn_out_w, WTfout, 4608, 1152);
  k_gemm<5><<<dim3(72, 64), 256, 0, stream>>>(NB, WTfin, nullptr, nullptr, nullptr,
                                              nullptr, XG, TOKENS, 9216, 1152);
  k_gemm<2><<<dim3(9, 64), 256, 0, stream>>>(XG, WTfout, nullptr, G3, out, out,
                                             nullptr, TOKENS, 1152, 4608);
}

// Round 4
// 1691.308 us; speedup vs baseline: 1.5278x; 1.0638x over previous
//
#include <hip/hip_runtime.h>
#include <hip/hip_bf16.h>
#include <math.h>

#define TOKENS 8192
#define HDIM 1152
#define SEQ 2048
#define NHEADS 12
#define HEADD 96
#define NMEM 4
#define MEMD 128
#define FINNER 4608

typedef __hip_bfloat16 bf16;
typedef __attribute__((ext_vector_type(8))) short short8;
typedef __attribute__((ext_vector_type(4))) float floatx4;

__device__ __constant__ int g_hd_dil[NHEADS * 3] = {
    1, 2, 4,   1, 1, 1,    4, 8, 16,   8, 16, 32,
    32, 64, 128, 64, 128, 256, 256, 512, 1024, 1, 100, 200,
    1, 500, 1000, 1, 1024, 2048, 3, 9, 27, 5, 25, 125};

__device__ inline float sigm(float x) { return 1.0f / (1.0f + expf(-x)); }
__device__ inline float gelu_exact(float x) {
  return 0.5f * x * (1.0f + erff(x * 0.70710678118654752f));
}
__device__ inline float wred(float v) {
#pragma unroll
  for (int o = 32; o > 0; o >>= 1) v += __shfl_down(v, o);
  return v;
}
// async global->LDS, 16B per lane; LDS dest must be wave-uniform base
__device__ inline void gl_lds16(const bf16* g, bf16* l) {
  __builtin_amdgcn_global_load_lds(
      (const __attribute__((address_space(1))) unsigned int*)g,
      (__attribute__((address_space(3))) unsigned int*)l, 16, 0, 0);
}

// ---------------- transpose f32 [K,N] -> bf16 [N,K] ----------------
__global__ __launch_bounds__(256) void k_transpose_bf16(
    const float* __restrict__ W, bf16* __restrict__ WT, int K, int N) {
  __shared__ float t[32][33];
  int k0 = blockIdx.y * 32, n0 = blockIdx.x * 32;
  int tx = threadIdx.x & 31, ty = threadIdx.x >> 5;
#pragma unroll
  for (int i = 0; i < 32; i += 8)
    t[ty + i][tx] = W[(size_t)(k0 + ty + i) * N + (n0 + tx)];
  __syncthreads();
#pragma unroll
  for (int i = 0; i < 32; i += 8)
    WT[(size_t)(n0 + ty + i) * K + (k0 + tx)] = __float2bfloat16(t[tx][ty + i]);
}

// ---- pair-permuted transpose: out row 2c = W[:,c], row 2c+1 = W[:,half+c] ----
__global__ __launch_bounds__(256) void k_transpose_pair(
    const float* __restrict__ W, bf16* __restrict__ WT, int K, int N) {
  __shared__ float t[32][33];
  int half = N >> 1;
  int k0 = blockIdx.y * 32, n0 = blockIdx.x * 32;
  int tx = threadIdx.x & 31, ty = threadIdx.x >> 5;
  int c = (tx < 16) ? (n0 / 2 + tx) : (half + n0 / 2 + tx - 16);
#pragma unroll
  for (int i = 0; i < 32; i += 8)
    t[ty + i][tx] = W[(size_t)(k0 + ty + i) * N + c];
  __syncthreads();
#pragma unroll
  for (int i = 0; i < 32; i += 8) {
    int r = ty + i;
    int cc = (r >> 1) + (r & 1) * 16;
    WT[(size_t)(n0 + r) * K + (k0 + tx)] = __float2bfloat16(t[tx][cc]);
  }
}

// ---------------- rmsnorm + scalar gate (+ optional fused router) ----------------
__global__ __launch_bounds__(256) void k_rms_gate(
    const float* __restrict__ x, const float* __restrict__ nw,
    const float* __restrict__ gw, const float* __restrict__ gb,
    bf16* __restrict__ outb, float* outf, float* __restrict__ gout,
    int writef, const float* __restrict__ rw, const float* __restrict__ rb,
    float* __restrict__ hwout) {
  __shared__ float r1[4], r2[4];
  __shared__ float rr[4][NHEADS];
  int tok = blockIdx.x;
  int tid = threadIdx.x;
  const float* row = x + (size_t)tok * HDIM;
  float a[5];
  float s2 = 0.f, gd = 0.f;
  for (int i = tid, k = 0; i < HDIM; i += 256, ++k) {
    float v = row[i];
    a[k] = v;
    s2 += v * v;
    gd += v * gw[i];
  }
  s2 = wred(s2);
  gd = wred(gd);
  int wave = tid >> 6, lane = tid & 63;
  if (lane == 0) {
    r1[wave] = s2;
    r2[wave] = gd;
  }
  __syncthreads();
  s2 = r1[0] + r1[1] + r1[2] + r1[3];
  gd = r2[0] + r2[1] + r2[2] + r2[3];
  float rn = 1.0f / sqrtf(s2 / (float)HDIM + 1e-6f);
  if (tid == 0) gout[tok] = sigm(gd + gb[0]);
  float racc[NHEADS] = {};
  for (int i = tid, k = 0; i < HDIM; i += 256, ++k) {
    float nv = a[k] * rn * nw[i];
    outb[(size_t)tok * HDIM + i] = __float2bfloat16(nv);
    if (writef) outf[(size_t)tok * HDIM + i] = nv;
    if (hwout) {
      const float* rp = &rw[(size_t)i * NHEADS];
#pragma unroll
      for (int o = 0; o < NHEADS; ++o) racc[o] += nv * rp[o];
    }
  }
  if (hwout) {
#pragma unroll
    for (int o = 0; o < NHEADS; ++o) racc[o] = wred(racc[o]);
    if (lane == 0)
#pragma unroll
      for (int o = 0; o < NHEADS; ++o) rr[wave][o] = racc[o];
    __syncthreads();
    if (tid < NHEADS) {
      float s = rr[0][tid] + rr[1][tid] + rr[2][tid] + rr[3][tid];
      hwout[(size_t)tok * NHEADS + tid] = sigm(s + rb[tid]);
    }
  }
}

// ---------------- fused conv stack: 6 dilated stages in LDS ----------------
#define CS_T 256
#define CS_HALO 189
#define CS_ROWS 445
__global__ __launch_bounds__(256) void k_convstack(
    const float* __restrict__ hin, bf16* __restrict__ outb,
    const float* __restrict__ cw, const float* __restrict__ cb) {
  extern __shared__ float lds[];
  float* cur = lds;
  float* nxt = lds + CS_ROWS * 32;
  int bx = blockIdx.x;
  int cs = bx % 36;
  int tile = (bx / 36) & 7;
  int b = bx / 288;
  int c0 = cs * 32;
  int S0 = tile * CS_T;
  int tid = threadIdx.x;
  int c = tid & 31;
  for (int i = tid; i < CS_ROWS * 32; i += 256) {
    int p = i >> 5, cc = i & 31;
    int sg = S0 - CS_HALO + p;
    cur[i] = (sg >= 0) ? hin[((size_t)(b * SEQ + sg)) * HDIM + c0 + cc] : 0.f;
  }
  const int dil[6] = {1, 2, 4, 8, 16, 32};
  const int Nk[6] = {3, 9, 21, 45, 93, 189};
#pragma unroll
  for (int k = 0; k < 6; ++k) {
    int d = dil[k];
    float w0 = cw[((size_t)k * HDIM + c0 + c) * 4 + 0];
    float w1 = cw[((size_t)k * HDIM + c0 + c) * 4 + 1];
    float w2 = cw[((size_t)k * HDIM + c0 + c) * 4 + 2];
    float w3 = cw[((size_t)k * HDIM + c0 + c) * 4 + 3];
    float bb = cb[(size_t)k * HDIM + c0 + c];
    __syncthreads();
    for (int p = Nk[k] + (tid >> 5); p < CS_ROWS; p += 8) {
      int i = p * 32 + c;
      int sg = S0 - CS_HALO + p;
      float acc = bb + w0 * cur[i - 3 * d * 32] + w1 * cur[i - 2 * d * 32] +
                  w2 * cur[i - d * 32] + w3 * cur[i];
      nxt[i] = (sg >= 0) ? (cur[i] + gelu_exact(acc)) : 0.f;
    }
    float* t = cur;
    cur = nxt;
    nxt = t;
  }
  __syncthreads();
  for (int r = tid >> 5; r < CS_T; r += 8) {
    outb[((size_t)(b * SEQ + S0 + r)) * HDIM + c0 + c] =
        __float2bfloat16(cur[(CS_HALO + r) * 32 + c]);
  }
}

// ---------------- per-head conv step j: h = h + dconv(h) ----------------
__global__ __launch_bounds__(256) void k_headconv(
    const float* __restrict__ hin, float* __restrict__ hout,
    const float* __restrict__ hw_, const float* __restrict__ hb_, int j) {
  size_t idx = (size_t)blockIdx.x * 256 + threadIdx.x;
  if (idx >= (size_t)TOKENS * HDIM) return;
  int c = (int)(idx % HDIM);
  int head = c / HEADD, hd = c % HEADD;
  size_t tok = idx / HDIM;
  int s = (int)(tok % SEQ);
  int d = g_hd_dil[head * 3 + j];
  const float* w = hw_ + ((size_t)(head * 3 + j) * HEADD + hd) * 4;
  float acc = hb_[(head * 3 + j) * HEADD + hd];
#pragma unroll
  for (int jj = 0; jj < 4; ++jj) {
    int back = (3 - jj) * d;
    if (s - back >= 0) acc += w[jj] * hin[idx - (size_t)back * HDIM];
  }
  hout[idx] = hin[idx] + acc;
}

// ---------------- GEMM (m97-style global_load_lds staging) ----------------
// C[M,N] = A[M,K](bf16) * BT[N,K](bf16)^T
// MODE 2: out = addin + gate[m]*(acc+bias)
// MODE 4: pair-GLU -> a*sigm(g) f32 (N halves)
// MODE 5: pair-GLU -> bf16 (N halves)
// MODE 6: outb = bf16(addin * sigm(acc+bias))
template <int MODE>
__global__ __launch_bounds__(256) void k_gemm(
    const bf16* __restrict__ A, const bf16* __restrict__ BT,
    const float* __restrict__ bias, const float* __restrict__ gate,
    const float* addin, float* outf, bf16* outb, int M, int N, int K) {
  __shared__ bf16 As[128 * 32];
  __shared__ bf16 Bs[128 * 32];
  const int tid = threadIdx.x;
  const int m0 = blockIdx.y * 128, n0 = blockIdx.x * 128;
  const int wave = tid >> 6, lane = tid & 63;
  const int wm = (wave & 1) * 64, wn = (wave >> 1) * 64;
  const int l16 = lane & 15, kq = lane >> 4;
  // staging: each wave fills rows [wave*32, wave*32+32) of As and Bs
  const int srow = wave * 32 + (lane >> 2);
  const int scol = (lane & 3) * 8;
  const bf16* gA = A + (size_t)(m0 + srow) * K + scol;
  const bf16* gB = BT + (size_t)(n0 + srow) * K + scol;
  bf16* lA = &As[wave * 32 * 32];
  bf16* lB = &Bs[wave * 32 * 32];
  floatx4 acc[4][4];
  floatx4 zero = {0.f, 0.f, 0.f, 0.f};
#pragma unroll
  for (int i = 0; i < 4; ++i)
#pragma unroll
    for (int jj = 0; jj < 4; ++jj) acc[i][jj] = zero;

  for (int k0 = 0; k0 < K; k0 += 32) {
    __syncthreads();
    gl_lds16(gA + k0, lA);
    gl_lds16(gA + k0 + (size_t)16 * K, lA + 16 * 32);
    gl_lds16(gB + k0, lB);
    gl_lds16(gB + k0 + (size_t)16 * K, lB + 16 * 32);
    __syncthreads();
    short8 af[4], bfr[4];
#pragma unroll
    for (int t = 0; t < 4; ++t) {
      af[t] = *reinterpret_cast<const short8*>(&As[(wm + t * 16 + l16) * 32 + kq * 8]);
      bfr[t] = *reinterpret_cast<const short8*>(&Bs[(wn + t * 16 + l16) * 32 + kq * 8]);
    }
#pragma unroll
    for (int mt = 0; mt < 4; ++mt)
#pragma unroll
      for (int nt = 0; nt < 4; ++nt)
        acc[mt][nt] = __builtin_amdgcn_mfma_f32_16x16x32_bf16(
            af[mt], bfr[nt], acc[mt][nt], 0, 0, 0);
  }

  if (MODE == 4 || MODE == 5) {
    const int halfN = N >> 1;
#pragma unroll
    for (int mt = 0; mt < 4; ++mt) {
#pragma unroll
      for (int nt = 0; nt < 4; ++nt) {
        int nn = n0 + wn + nt * 16 + l16;
#pragma unroll
        for (int r = 0; r < 4; ++r) {
          float v = acc[mt][nt][r];
          float g = __shfl_xor(v, 1);
          if ((lane & 1) == 0) {
            int m = m0 + wm + mt * 16 + kq * 4 + r;
            float res = v * sigm(g);
            size_t o = (size_t)m * halfN + (nn >> 1);
            if (MODE == 4) outf[o] = res;
            else outb[o] = __float2bfloat16(res);
          }
        }
      }
    }
    return;
  }

#pragma unroll
  for (int mt = 0; mt < 4; ++mt) {
#pragma unroll
    for (int nt = 0; nt < 4; ++nt) {
      int n = n0 + wn + nt * 16 + l16;
      float bv = bias ? bias[n] : 0.f;
#pragma unroll
      for (int r = 0; r < 4; ++r) {
        int m = m0 + wm + mt * 16 + kq * 4 + r;
        float v = acc[mt][nt][r] + bv;
        size_t o = (size_t)m * N + n;
        if (MODE == 2) outf[o] = addin[o] + gate[m] * v;
        else if (MODE == 6) outb[o] = __float2bfloat16(addin[o] * sigm(v));
      }
    }
  }
}

// ---------------- memory q/kg/v/g projections ----------------
__global__ __launch_bounds__(256) void k_qkvg(
    const float* __restrict__ xh, const float* __restrict__ Wq,
    const float* __restrict__ Wk, const float* __restrict__ Wv,
    const float* __restrict__ gw, const float* __restrict__ gb,
    float* __restrict__ q, float* __restrict__ kg, float* __restrict__ v,
    float* __restrict__ gout) {
  __shared__ float xm[NMEM * HEADD];
  __shared__ float gsh[NMEM];
  int tok = blockIdx.x, tid = threadIdx.x;
  for (int i = tid; i < NMEM * HEADD; i += 256)
    xm[i] = xh[(size_t)tok * HDIM + 6 * HEADD + i];
  __syncthreads();
  if (tid < NMEM) {
    float a = gb[tid];
    for (int d = 0; d < HEADD; ++d) a += xm[tid * HEADD + d] * gw[tid * HEADD + d];
    float s = sigm(a);
    gsh[tid] = s;
    gout[tok * NMEM + tid] = s;
  }
  __syncthreads();
  for (int i = tid; i < 1280; i += 256) {
    if (i < 384) {
      int n = i / HEADD, e = i % HEADD;
      const float* W = Wq + (size_t)n * HEADD * HEADD + e;
      const float* xr = xm + n * HEADD;
      float a = 0.f;
      for (int d = 0; d < HEADD; ++d) a += xr[d] * W[(size_t)d * HEADD];
      q[(size_t)tok * 384 + i] = a;
    } else if (i < 768) {
      int i2 = i - 384;
      int n = i2 / HEADD, e = i2 % HEADD;
      const float* W = Wk + (size_t)n * HEADD * HEADD + e;
      const float* xr = xm + n * HEADD;
      float a = 0.f;
      for (int d = 0; d < HEADD; ++d) a += xr[d] * W[(size_t)d * HEADD];
      kg[(size_t)tok * 384 + i2] = a * gsh[n];
    } else {
      int i2 = i - 768;
      int n = i2 / MEMD, e = i2 % MEMD;
      const float* W = Wv + (size_t)n * HEADD * MEMD + e;
      const float* xr = xm + n * HEADD;
      float a = 0.f;
      for (int d = 0; d < HEADD; ++d) a += xr[d] * W[(size_t)d * MEMD];
      v[(size_t)tok * 512 + i2] = a;
    }
  }
}

// ---------------- chunk means of g ----------------
__global__ __launch_bounds__(256) void k_gmean(const float* __restrict__ g,
                                               float* __restrict__ ga) {
  int idx = blockIdx.x * 256 + threadIdx.x;
  if (idx >= 512) return;
  int b = idx >> 7, ch = (idx >> 2) & 31, n = idx & 3;
  float s = 0.f;
  for (int t = 0; t < 64; ++t)
    s += g[((size_t)b * SEQ + ch * 64 + t) * NMEM + n];
  ga[idx] = s * (1.0f / 64.0f);
}

// ---------------- pass 1: per-chunk writes W[bnc][96][128] ----------------
__global__ __launch_bounds__(256) void k_memW(const float* __restrict__ kg,
                                              const float* __restrict__ v,
                                              float* __restrict__ W) {
  __shared__ float X[64 * 96];
  __shared__ float V[64 * 128];
  int bx = blockIdx.x;
  int bn = bx >> 5, ch = bx & 31;
  int b = bn >> 2, n = bn & 3;
  int t0 = b * SEQ + ch * 64;
  int tid = threadIdx.x;
  for (int i = tid; i < 64 * 96; i += 256) {
    int s = i / 96, d = i % 96;
    X[i] = kg[((size_t)(t0 + s) * NMEM + n) * HEADD + d];
  }
  for (int i = tid; i < 64 * 128; i += 256) {
    int s = i >> 7, m = i & 127;
    V[i] = v[((size_t)(t0 + s) * NMEM + n) * MEMD + m];
  }
  __syncthreads();
  float* Wb = W + (size_t)bx * 96 * 128;
  for (int t = tid; t < 768; t += 256) {
    int d0 = (t >> 5) * 4, m0 = (t & 31) * 4;
    float acc[4][4] = {};
    for (int s = 0; s < 64; ++s) {
      float4 xv = *reinterpret_cast<const float4*>(&X[s * 96 + d0]);
      float4 vv = *reinterpret_cast<const float4*>(&V[s * 128 + m0]);
      float xa[4] = {xv.x, xv.y, xv.z, xv.w};
      float va[4] = {vv.x, vv.y, vv.z, vv.w};
#pragma unroll
      for (int a = 0; a < 4; ++a)
#pragma unroll
        for (int e = 0; e < 4; ++e) acc[a][e] += xa[a] * va[e];
    }
#pragma unroll
    for (int a = 0; a < 4; ++a) {
      float4 o = {acc[a][0], acc[a][1], acc[a][2], acc[a][3]};
      *reinterpret_cast<float4*>(&Wb[(size_t)(d0 + a) * 128 + m0]) = o;
    }
  }
}

// ---------------- pass 2: prefix scan over chunks ----------------
__global__ __launch_bounds__(256) void k_memscanM(const float* __restrict__ W,
                                                  const float* __restrict__ ga,
                                                  float* __restrict__ Mp) {
  int bx = blockIdx.x;
  int bn = bx / 48, j = bx % 48;
  int elem = j * 256 + threadIdx.x;
  int b = bn >> 2, n = bn & 3;
  float M = 0.f;
  for (int ch = 0; ch < 32; ++ch) {
    size_t base = ((size_t)bn * 32 + ch) * 12288 + elem;
    Mp[base] = M;
    float g = ga[(b * 32 + ch) * NMEM + n];
    M = (1.f - g) * M + W[base];
  }
}

// ---------------- pass 3: reads = q @ M_prefix ----------------
__global__ __launch_bounds__(256) void k_memR(const float* __restrict__ q,
                                              const float* __restrict__ Mp,
                                              float* __restrict__ rd) {
  extern __shared__ float smem[];
  float* Q = smem;
  float* Ms = smem + 64 * 96;
  int bx = blockIdx.x;
  int bn = bx >> 5, ch = bx & 31;
  int b = bn >> 2, n = bn & 3;
  int t0 = b * SEQ + ch * 64;
  int tid = threadIdx.x;
  for (int i = tid; i < 64 * 96; i += 256) {
    int s = i / 96, d = i % 96;
    Q[i] = q[((size_t)(t0 + s) * NMEM + n) * HEADD + d];
  }
  for (int i = tid; i < 96 * 128; i += 256)
    Ms[i] = Mp[((size_t)bn * 32 + ch) * 12288 + i];
  __syncthreads();
  for (int t = tid; t < 512; t += 256) {
    int s0 = (t >> 5) * 4, m0 = (t & 31) * 4;
    float acc[4][4] = {};
    for (int k = 0; k < 96; ++k) {
      float4 mv = *reinterpret_cast<const float4*>(&Ms[k * 128 + m0]);
      float ma[4] = {mv.x, mv.y, mv.z, mv.w};
#pragma unroll
      for (int si = 0; si < 4; ++si) {
        float qs = Q[(s0 + si) * 96 + k];
#pragma unroll
        for (int mi = 0; mi < 4; ++mi) acc[si][mi] += qs * ma[mi];
      }
    }
#pragma unroll
    for (int si = 0; si < 4; ++si) {
      float4 o = {acc[si][0], acc[si][1], acc[si][2], acc[si][3]};
      *reinterpret_cast<float4*>(
          &rd[((size_t)(t0 + s0 + si) * NMEM + n) * MEMD + m0]) = o;
    }
  }
}

// ---------------- combine: out = (hconv + memproj) * head_weight ----------------
__global__ __launch_bounds__(256) void k_combine(
    const float* __restrict__ hconv, const float* __restrict__ reads,
    const float* __restrict__ Wout, const float* __restrict__ hw,
    float* __restrict__ outf, bf16* __restrict__ outb) {
  __shared__ float rd[NMEM * MEMD];
  int tok = blockIdx.x, tid = threadIdx.x;
  for (int i = tid; i < NMEM * MEMD; i += 256)
    rd[i] = reads[(size_t)tok * NMEM * MEMD + i];
  __syncthreads();
  for (int c = tid; c < HDIM; c += 256) {
    int head = c / HEADD, hd = c % HEADD;
    float v = hconv[(size_t)tok * HDIM + c];
    if (head >= 6 && head < 10) {
      int n = head - 6;
      const float* W = Wout + (size_t)(n * MEMD) * HEADD + hd;
      for (int m2 = 0; m2 < MEMD; ++m2) v += rd[n * MEMD + m2] * W[(size_t)m2 * HEADD];
    }
    v *= hw[tok * NHEADS + head];
    outf[(size_t)tok * HDIM + c] = v;
    outb[(size_t)tok * HDIM + c] = __float2bfloat16(v);
  }
}

extern "C" void kernel_launch(void* const* d_in, const int* in_sizes, int n_in,
                              void* d_out, int out_size, void* d_ws,
                              size_t ws_size, hipStream_t stream) {
  const float* x_in = (const float*)d_in[0];
  const float* norm1_w = (const float*)d_in[1];
  const float* norm2_w = (const float*)d_in[2];
  const float* norm3_w = (const float*)d_in[3];
  const float* cs_w = (const float*)d_in[4];
  const float* cs_b = (const float*)d_in[5];
  const float* cs_proj_w = (const float*)d_in[6];
  const float* cs_proj_b = (const float*)d_in[7];
  const float* gate_proj_w = (const float*)d_in[8];
  const float* router_w = (const float*)d_in[9];
  const float* router_b = (const float*)d_in[10];
  const float* head_w = (const float*)d_in[11];
  const float* head_b = (const float*)d_in[12];
  const float* mem_q = (const float*)d_in[13];
  const float* mem_k = (const float*)d_in[14];
  const float* mem_v = (const float*)d_in[15];
  const float* mem_gw = (const float*)d_in[16];
  const float* mem_gb = (const float*)d_in[17];
  const float* mem_out = (const float*)d_in[18];
  const float* mixgate_w = (const float*)d_in[19];
  const float* mixgate_b = (const float*)d_in[20];
  const float* mixing_w = (const float*)d_in[21];
  const float* mixing_b = (const float*)d_in[22];
  const float* ffn_in_w = (const float*)d_in[23];
  const float* ffn_out_w = (const float*)d_in[24];
  const float* cg_w = (const float*)d_in[25];
  const float* cg_b = (const float*)d_in[26];
  const float* sg_w = (const float*)d_in[27];
  const float* sg_b = (const float*)d_in[28];
  const float* fg_w = (const float*)d_in[29];
  const float* fg_b = (const float*)d_in[30];
  float* out = (float*)d_out;

  char* wsp = (char*)d_ws;
  size_t off = 0;
  auto alloc = [&](size_t bytes) -> char* {
    char* p = wsp + off;
    off += (bytes + 255) & ~(size_t)255;
    return p;
  };
  bf16* NB = (bf16*)alloc((size_t)TOKENS * HDIM * 2);
  float* F1 = (float*)alloc((size_t)TOKENS * HDIM * 4);
  float* F2 = (float*)alloc((size_t)TOKENS * HDIM * 4);
  float* F3 = (float*)alloc((size_t)TOKENS * HDIM * 4);
  char* REG = alloc((size_t)TOKENS * FINNER * 2);
  float* qb = (float*)REG;
  float* kgb = (float*)(REG + (size_t)TOKENS * 384 * 4);
  float* vb = (float*)((char*)kgb + (size_t)TOKENS * 384 * 4);
  float* rdb = (float*)((char*)vb + (size_t)TOKENS * 512 * 4);
  bf16* XG = (bf16*)REG;   // stage-C view
  bf16* NB2 = (bf16*)REG;  // mixgate output view (qb region dead by then)
  bf16* WTcs = (bf16*)alloc((size_t)1152 * 1152 * 2);
  bf16* WTgp = (bf16*)alloc((size_t)2304 * 1152 * 2);
  bf16* WTmg = (bf16*)alloc((size_t)1152 * 1152 * 2);
  bf16* WTmx = (bf16*)alloc((size_t)1152 * 1152 * 2);
  float* G1 = (float*)alloc(TOKENS * 4);
  float* G2 = (float*)alloc(TOKENS * 4);
  float* G3 = (float*)alloc(TOKENS * 4);
  float* GM = (float*)alloc((size_t)TOKENS * NMEM * 4);
  float* GA = (float*)alloc(4 * 32 * NMEM * 4);
  float* HW = (float*)alloc((size_t)TOKENS * NHEADS * 4);
  bf16* WTfin = (bf16*)F1;
  bf16* WTfout = (bf16*)F2;
  float* Wbuf = F2;
  float* Mpref = F3;

  const int gE = (TOKENS * HDIM) / 256;

  k_transpose_bf16<<<dim3(36, 36), 256, 0, stream>>>(cs_proj_w, WTcs, 1152, 1152);
  k_transpose_pair<<<dim3(72, 36), 256, 0, stream>>>(gate_proj_w, WTgp, 1152, 2304);
  k_transpose_bf16<<<dim3(36, 36), 256, 0, stream>>>(mixgate_w, WTmg, 1152, 1152);
  k_transpose_bf16<<<dim3(36, 36), 256, 0, stream>>>(mixing_w, WTmx, 1152, 1152);

  // ---- stage A: conv stack ----
  k_rms_gate<<<TOKENS, 256, 0, stream>>>(x_in, norm1_w, cg_w, cg_b, NB, F1, G1, 1,
                                         nullptr, nullptr, nullptr);
  k_convstack<<<1152, 256, 2 * CS_ROWS * 32 * 4, stream>>>(F1, NB, cs_w, cs_b);
  k_gemm<2><<<dim3(9, 64), 256, 0, stream>>>(NB, WTcs, cs_proj_b, G1, x_in, out,
                                             nullptr, TOKENS, 1152, 1152);

  // ---- stage B: multi-head state ----
  k_rms_gate<<<TOKENS, 256, 0, stream>>>(out, norm2_w, sg_w, sg_b, NB, nullptr, G2,
                                         0, router_w, router_b, HW);
  k_gemm<4><<<dim3(18, 64), 256, 0, stream>>>(NB, WTgp, nullptr, nullptr, nullptr,
                                              F3, nullptr, TOKENS, 2304, 1152);
  k_headconv<<<gE, 256, 0, stream>>>(F3, F1, head_w, head_b, 0);
  k_headconv<<<gE, 256, 0, stream>>>(F1, F2, head_w, head_b, 1);
  k_headconv<<<gE, 256, 0, stream>>>(F2, F1, head_w, head_b, 2);
  k_qkvg<<<TOKENS, 256, 0, stream>>>(F3, mem_q, mem_k, mem_v, mem_gw, mem_gb,
                                     qb, kgb, vb, GM);
  k_gmean<<<2, 256, 0, stream>>>(GM, GA);
  k_memW<<<512, 256, 0, stream>>>(kgb, vb, Wbuf);
  k_memscanM<<<768, 256, 0, stream>>>(Wbuf, GA, Mpref);
  k_memR<<<512, 256, (64 * 96 + 96 * 128) * 4, stream>>>(qb, Mpref, rdb);
  k_combine<<<TOKENS, 256, 0, stream>>>(F1, rdb, mem_out, HW, F2, NB);
  // fused mixgate: NB2 = bf16(F2 * sigm(NB@mixgate + b))
  k_gemm<6><<<dim3(9, 64), 256, 0, stream>>>(NB, WTmg, mixgate_b, nullptr, F2,
                                             nullptr, NB2, TOKENS, 1152, 1152);
  k_gemm<2><<<dim3(9, 64), 256, 0, stream>>>(NB2, WTmx, mixing_b, G2, out, out,
                                             nullptr, TOKENS, 1152, 1152);

  // ---- stage C: GLU FFN ----
  k_rms_gate<<<TOKENS, 256, 0, stream>>>(out, norm3_w, fg_w, fg_b, NB, nullptr, G3,
                                         0, nullptr, nullptr, nullptr);
  k_transpose_pair<<<dim3(288, 36), 256, 0, stream>>>(ffn_in_w, WTfin, 1152, 9216);
  k_transpose_bf16<<<dim3(36, 144), 256, 0, stream>>>(ffn_out_w, WTfout, 4608, 1152);
  k_gemm<5><<<dim3(72, 64), 256, 0, stream>>>(NB, WTfin, nullptr, nullptr, nullptr,
                                              nullptr, XG, TOKENS, 9216, 1152);
  k_gemm<2><<<dim3(9, 64), 256, 0, stream>>>(XG, WTfout, nullptr, G3, out, out,
                                             nullptr, TOKENS, 1152, 4608);
}

// Round 5
// 1685.907 us; speedup vs baseline: 1.5327x; 1.0032x over previous
//
#include <hip/hip_runtime.h>
#include <hip/hip_bf16.h>
#include <math.h>

#define TOKENS 8192
#define HDIM 1152
#define SEQ 2048
#define NHEADS 12
#define HEADD 96
#define NMEM 4
#define MEMD 128
#define FINNER 4608

typedef __hip_bfloat16 bf16;
typedef __attribute__((ext_vector_type(8))) short short8;
typedef __attribute__((ext_vector_type(4))) float floatx4;

__device__ __constant__ int g_hd_dil[NHEADS * 3] = {
    1, 2, 4,   1, 1, 1,    4, 8, 16,   8, 16, 32,
    32, 64, 128, 64, 128, 256, 256, 512, 1024, 1, 100, 200,
    1, 500, 1000, 1, 1024, 2048, 3, 9, 27, 5, 25, 125};

__device__ inline float sigm(float x) { return 1.0f / (1.0f + expf(-x)); }
__device__ inline float gelu_exact(float x) {
  return 0.5f * x * (1.0f + erff(x * 0.70710678118654752f));
}
__device__ inline float wred(float v) {
#pragma unroll
  for (int o = 32; o > 0; o >>= 1) v += __shfl_down(v, o);
  return v;
}
// async global->LDS, 16B per lane; LDS dest wave-uniform base + lane*16
__device__ inline void gl_lds16(const bf16* g, bf16* l) {
  __builtin_amdgcn_global_load_lds(
      (const __attribute__((address_space(1))) unsigned int*)g,
      (__attribute__((address_space(3))) unsigned int*)l, 16, 0, 0);
}

// ---------------- transpose f32 [K,N] -> bf16 [N,K] ----------------
__global__ __launch_bounds__(256) void k_transpose_bf16(
    const float* __restrict__ W, bf16* __restrict__ WT, int K, int N) {
  __shared__ float t[32][33];
  int k0 = blockIdx.y * 32, n0 = blockIdx.x * 32;
  int tx = threadIdx.x & 31, ty = threadIdx.x >> 5;
#pragma unroll
  for (int i = 0; i < 32; i += 8)
    t[ty + i][tx] = W[(size_t)(k0 + ty + i) * N + (n0 + tx)];
  __syncthreads();
#pragma unroll
  for (int i = 0; i < 32; i += 8)
    WT[(size_t)(n0 + ty + i) * K + (k0 + tx)] = __float2bfloat16(t[tx][ty + i]);
}

// ---- pair-permuted transpose: out row 2c = W[:,c], row 2c+1 = W[:,half+c] ----
__global__ __launch_bounds__(256) void k_transpose_pair(
    const float* __restrict__ W, bf16* __restrict__ WT, int K, int N) {
  __shared__ float t[32][33];
  int half = N >> 1;
  int k0 = blockIdx.y * 32, n0 = blockIdx.x * 32;
  int tx = threadIdx.x & 31, ty = threadIdx.x >> 5;
  int c = (tx < 16) ? (n0 / 2 + tx) : (half + n0 / 2 + tx - 16);
#pragma unroll
  for (int i = 0; i < 32; i += 8)
    t[ty + i][tx] = W[(size_t)(k0 + ty + i) * N + c];
  __syncthreads();
#pragma unroll
  for (int i = 0; i < 32; i += 8) {
    int r = ty + i;
    int cc = (r >> 1) + (r & 1) * 16;
    WT[(size_t)(n0 + r) * K + (k0 + tx)] = __float2bfloat16(t[tx][cc]);
  }
}

// ---------------- rmsnorm + scalar gate (+ optional fused router) ----------------
__global__ __launch_bounds__(256) void k_rms_gate(
    const float* __restrict__ x, const float* __restrict__ nw,
    const float* __restrict__ gw, const float* __restrict__ gb,
    bf16* __restrict__ outb, float* outf, float* __restrict__ gout,
    int writef, const float* __restrict__ rw, const float* __restrict__ rb,
    float* __restrict__ hwout) {
  __shared__ float r1[4], r2[4];
  __shared__ float rr[4][NHEADS];
  int tok = blockIdx.x;
  int tid = threadIdx.x;
  const float* row = x + (size_t)tok * HDIM;
  float a[5];
  float s2 = 0.f, gd = 0.f;
  for (int i = tid, k = 0; i < HDIM; i += 256, ++k) {
    float v = row[i];
    a[k] = v;
    s2 += v * v;
    gd += v * gw[i];
  }
  s2 = wred(s2);
  gd = wred(gd);
  int wave = tid >> 6, lane = tid & 63;
  if (lane == 0) {
    r1[wave] = s2;
    r2[wave] = gd;
  }
  __syncthreads();
  s2 = r1[0] + r1[1] + r1[2] + r1[3];
  gd = r2[0] + r2[1] + r2[2] + r2[3];
  float rn = 1.0f / sqrtf(s2 / (float)HDIM + 1e-6f);
  if (tid == 0) gout[tok] = sigm(gd + gb[0]);
  float racc[NHEADS] = {};
  for (int i = tid, k = 0; i < HDIM; i += 256, ++k) {
    float nv = a[k] * rn * nw[i];
    outb[(size_t)tok * HDIM + i] = __float2bfloat16(nv);
    if (writef) outf[(size_t)tok * HDIM + i] = nv;
    if (hwout) {
      const float* rp = &rw[(size_t)i * NHEADS];
#pragma unroll
      for (int o = 0; o < NHEADS; ++o) racc[o] += nv * rp[o];
    }
  }
  if (hwout) {
#pragma unroll
    for (int o = 0; o < NHEADS; ++o) racc[o] = wred(racc[o]);
    if (lane == 0)
#pragma unroll
      for (int o = 0; o < NHEADS; ++o) rr[wave][o] = racc[o];
    __syncthreads();
    if (tid < NHEADS) {
      float s = rr[0][tid] + rr[1][tid] + rr[2][tid] + rr[3][tid];
      hwout[(size_t)tok * NHEADS + tid] = sigm(s + rb[tid]);
    }
  }
}

// ---------------- fused conv stack: 6 dilated stages in LDS ----------------
#define CS_T 256
#define CS_HALO 189
#define CS_ROWS 445
__global__ __launch_bounds__(256) void k_convstack(
    const float* __restrict__ hin, bf16* __restrict__ outb,
    const float* __restrict__ cw, const float* __restrict__ cb) {
  extern __shared__ float lds[];
  float* cur = lds;
  float* nxt = lds + CS_ROWS * 32;
  int bx = blockIdx.x;
  int cs = bx % 36;
  int tile = (bx / 36) & 7;
  int b = bx / 288;
  int c0 = cs * 32;
  int S0 = tile * CS_T;
  int tid = threadIdx.x;
  int c = tid & 31;
  for (int i = tid; i < CS_ROWS * 32; i += 256) {
    int p = i >> 5, cc = i & 31;
    int sg = S0 - CS_HALO + p;
    cur[i] = (sg >= 0) ? hin[((size_t)(b * SEQ + sg)) * HDIM + c0 + cc] : 0.f;
  }
  const int dil[6] = {1, 2, 4, 8, 16, 32};
  const int Nk[6] = {3, 9, 21, 45, 93, 189};
#pragma unroll
  for (int k = 0; k < 6; ++k) {
    int d = dil[k];
    float w0 = cw[((size_t)k * HDIM + c0 + c) * 4 + 0];
    float w1 = cw[((size_t)k * HDIM + c0 + c) * 4 + 1];
    float w2 = cw[((size_t)k * HDIM + c0 + c) * 4 + 2];
    float w3 = cw[((size_t)k * HDIM + c0 + c) * 4 + 3];
    float bb = cb[(size_t)k * HDIM + c0 + c];
    __syncthreads();
    for (int p = Nk[k] + (tid >> 5); p < CS_ROWS; p += 8) {
      int i = p * 32 + c;
      int sg = S0 - CS_HALO + p;
      float acc = bb + w0 * cur[i - 3 * d * 32] + w1 * cur[i - 2 * d * 32] +
                  w2 * cur[i - d * 32] + w3 * cur[i];
      nxt[i] = (sg >= 0) ? (cur[i] + gelu_exact(acc)) : 0.f;
    }
    float* t = cur;
    cur = nxt;
    nxt = t;
  }
  __syncthreads();
  for (int r = tid >> 5; r < CS_T; r += 8) {
    outb[((size_t)(b * SEQ + S0 + r)) * HDIM + c0 + c] =
        __float2bfloat16(cur[(CS_HALO + r) * 32 + c]);
  }
}

// ---------------- per-head conv step j: h = h + dconv(h) ----------------
__global__ __launch_bounds__(256) void k_headconv(
    const float* __restrict__ hin, float* __restrict__ hout,
    const float* __restrict__ hw_, const float* __restrict__ hb_, int j) {
  size_t idx = (size_t)blockIdx.x * 256 + threadIdx.x;
  if (idx >= (size_t)TOKENS * HDIM) return;
  int c = (int)(idx % HDIM);
  int head = c / HEADD, hd = c % HEADD;
  size_t tok = idx / HDIM;
  int s = (int)(tok % SEQ);
  int d = g_hd_dil[head * 3 + j];
  const float* w = hw_ + ((size_t)(head * 3 + j) * HEADD + hd) * 4;
  float acc = hb_[(head * 3 + j) * HEADD + hd];
#pragma unroll
  for (int jj = 0; jj < 4; ++jj) {
    int back = (3 - jj) * d;
    if (s - back >= 0) acc += w[jj] * hin[idx - (size_t)back * HDIM];
  }
  hout[idx] = hin[idx] + acc;
}

// ---------------- GEMM (global_load_lds staging + swizzled LDS) ----------------
// C[M,N] = A[M,K](bf16) * BT[N,K](bf16)^T
// Swizzle: LDS slot (row, sc) holds k-chunk (sc - (row>>1)) & 3. Staging lane
// fetches the permuted chunk; fragment read uses column (kq + ((l16>>1)&3))&3.
// Kills the 8-way bank-group conflict of the linear layout.
// MODE 2: out = addin + gate[m]*(acc+bias)
// MODE 4: pair-GLU -> a*sigm(g) f32 (N halves)
// MODE 5: pair-GLU -> bf16 (N halves)
// MODE 6: outb = bf16(addin * sigm(acc+bias))
template <int MODE>
__global__ __launch_bounds__(256) void k_gemm(
    const bf16* __restrict__ A, const bf16* __restrict__ BT,
    const float* __restrict__ bias, const float* __restrict__ gate,
    const float* addin, float* outf, bf16* outb, int M, int N, int K) {
  __shared__ bf16 As[128 * 32];
  __shared__ bf16 Bs[128 * 32];
  const int tid = threadIdx.x;
  const int m0 = blockIdx.y * 128, n0 = blockIdx.x * 128;
  const int wave = tid >> 6, lane = tid & 63;
  const int wm = (wave & 1) * 64, wn = (wave >> 1) * 64;
  const int l16 = lane & 15, kq = lane >> 4;
  // staging: wave fills rows [wave*32, wave*32+32); lane writes slot lane*16B.
  // swizzled k-chunk for this lane:
  const int cprime = ((lane & 3) - ((lane >> 3) & 3)) & 3;
  const int srow = wave * 32 + (lane >> 2);
  const bf16* gA = A + (size_t)(m0 + srow) * K + cprime * 8;
  const bf16* gB = BT + (size_t)(n0 + srow) * K + cprime * 8;
  bf16* lA = &As[wave * 32 * 32];
  bf16* lB = &Bs[wave * 32 * 32];
  // fragment-read swizzled column (per-lane constant)
  const int rcol = ((kq + ((l16 >> 1) & 3)) & 3) * 8;
  floatx4 acc[4][4];
  floatx4 zero = {0.f, 0.f, 0.f, 0.f};
#pragma unroll
  for (int i = 0; i < 4; ++i)
#pragma unroll
    for (int jj = 0; jj < 4; ++jj) acc[i][jj] = zero;

  for (int k0 = 0; k0 < K; k0 += 32) {
    __syncthreads();
    gl_lds16(gA + k0, lA);
    gl_lds16(gA + k0 + (size_t)16 * K, lA + 16 * 32);
    gl_lds16(gB + k0, lB);
    gl_lds16(gB + k0 + (size_t)16 * K, lB + 16 * 32);
    __syncthreads();
    short8 af[4], bfr[4];
#pragma unroll
    for (int t = 0; t < 4; ++t) {
      af[t] = *reinterpret_cast<const short8*>(&As[(wm + t * 16 + l16) * 32 + rcol]);
      bfr[t] = *reinterpret_cast<const short8*>(&Bs[(wn + t * 16 + l16) * 32 + rcol]);
    }
#pragma unroll
    for (int mt = 0; mt < 4; ++mt)
#pragma unroll
      for (int nt = 0; nt < 4; ++nt)
        acc[mt][nt] = __builtin_amdgcn_mfma_f32_16x16x32_bf16(
            af[mt], bfr[nt], acc[mt][nt], 0, 0, 0);
  }

  if (MODE == 4 || MODE == 5) {
    const int halfN = N >> 1;
#pragma unroll
    for (int mt = 0; mt < 4; ++mt) {
#pragma unroll
      for (int nt = 0; nt < 4; ++nt) {
        int nn = n0 + wn + nt * 16 + l16;
#pragma unroll
        for (int r = 0; r < 4; ++r) {
          float v = acc[mt][nt][r];
          float g = __shfl_xor(v, 1);
          if ((lane & 1) == 0) {
            int m = m0 + wm + mt * 16 + kq * 4 + r;
            float res = v * sigm(g);
            size_t o = (size_t)m * halfN + (nn >> 1);
            if (MODE == 4) outf[o] = res;
            else outb[o] = __float2bfloat16(res);
          }
        }
      }
    }
    return;
  }

#pragma unroll
  for (int mt = 0; mt < 4; ++mt) {
#pragma unroll
    for (int nt = 0; nt < 4; ++nt) {
      int n = n0 + wn + nt * 16 + l16;
      float bv = bias ? bias[n] : 0.f;
#pragma unroll
      for (int r = 0; r < 4; ++r) {
        int m = m0 + wm + mt * 16 + kq * 4 + r;
        float v = acc[mt][nt][r] + bv;
        size_t o = (size_t)m * N + n;
        if (MODE == 2) outf[o] = addin[o] + gate[m] * v;
        else if (MODE == 6) outb[o] = __float2bfloat16(addin[o] * sigm(v));
      }
    }
  }
}

// ---------------- memory q/kg/v/g projections ----------------
__global__ __launch_bounds__(256) void k_qkvg(
    const float* __restrict__ xh, const float* __restrict__ Wq,
    const float* __restrict__ Wk, const float* __restrict__ Wv,
    const float* __restrict__ gw, const float* __restrict__ gb,
    float* __restrict__ q, float* __restrict__ kg, float* __restrict__ v,
    float* __restrict__ gout) {
  __shared__ float xm[NMEM * HEADD];
  __shared__ float gsh[NMEM];
  int tok = blockIdx.x, tid = threadIdx.x;
  for (int i = tid; i < NMEM * HEADD; i += 256)
    xm[i] = xh[(size_t)tok * HDIM + 6 * HEADD + i];
  __syncthreads();
  if (tid < NMEM) {
    float a = gb[tid];
    for (int d = 0; d < HEADD; ++d) a += xm[tid * HEADD + d] * gw[tid * HEADD + d];
    float s = sigm(a);
    gsh[tid] = s;
    gout[tok * NMEM + tid] = s;
  }
  __syncthreads();
  for (int i = tid; i < 1280; i += 256) {
    if (i < 384) {
      int n = i / HEADD, e = i % HEADD;
      const float* W = Wq + (size_t)n * HEADD * HEADD + e;
      const float* xr = xm + n * HEADD;
      float a = 0.f;
      for (int d = 0; d < HEADD; ++d) a += xr[d] * W[(size_t)d * HEADD];
      q[(size_t)tok * 384 + i] = a;
    } else if (i < 768) {
      int i2 = i - 384;
      int n = i2 / HEADD, e = i2 % HEADD;
      const float* W = Wk + (size_t)n * HEADD * HEADD + e;
      const float* xr = xm + n * HEADD;
      float a = 0.f;
      for (int d = 0; d < HEADD; ++d) a += xr[d] * W[(size_t)d * HEADD];
      kg[(size_t)tok * 384 + i2] = a * gsh[n];
    } else {
      int i2 = i - 768;
      int n = i2 / MEMD, e = i2 % MEMD;
      const float* W = Wv + (size_t)n * HEADD * MEMD + e;
      const float* xr = xm + n * HEADD;
      float a = 0.f;
      for (int d = 0; d < HEADD; ++d) a += xr[d] * W[(size_t)d * MEMD];
      v[(size_t)tok * 512 + i2] = a;
    }
  }
}

// ---------------- chunk means of g ----------------
__global__ __launch_bounds__(256) void k_gmean(const float* __restrict__ g,
                                               float* __restrict__ ga) {
  int idx = blockIdx.x * 256 + threadIdx.x;
  if (idx >= 512) return;
  int b = idx >> 7, ch = (idx >> 2) & 31, n = idx & 3;
  float s = 0.f;
  for (int t = 0; t < 64; ++t)
    s += g[((size_t)b * SEQ + ch * 64 + t) * NMEM + n];
  ga[idx] = s * (1.0f / 64.0f);
}

// ---------------- pass 1: per-chunk writes W[bnc][96][128] ----------------
__global__ __launch_bounds__(256) void k_memW(const float* __restrict__ kg,
                                              const float* __restrict__ v,
                                              float* __restrict__ W) {
  __shared__ float X[64 * 96];
  __shared__ float V[64 * 128];
  int bx = blockIdx.x;
  int bn = bx >> 5, ch = bx & 31;
  int b = bn >> 2, n = bn & 3;
  int t0 = b * SEQ + ch * 64;
  int tid = threadIdx.x;
  for (int i = tid; i < 64 * 96; i += 256) {
    int s = i / 96, d = i % 96;
    X[i] = kg[((size_t)(t0 + s) * NMEM + n) * HEADD + d];
  }
  for (int i = tid; i < 64 * 128; i += 256) {
    int s = i >> 7, m = i & 127;
    V[i] = v[((size_t)(t0 + s) * NMEM + n) * MEMD + m];
  }
  __syncthreads();
  float* Wb = W + (size_t)bx * 96 * 128;
  for (int t = tid; t < 768; t += 256) {
    int d0 = (t >> 5) * 4, m0 = (t & 31) * 4;
    float acc[4][4] = {};
    for (int s = 0; s < 64; ++s) {
      float4 xv = *reinterpret_cast<const float4*>(&X[s * 96 + d0]);
      float4 vv = *reinterpret_cast<const float4*>(&V[s * 128 + m0]);
      float xa[4] = {xv.x, xv.y, xv.z, xv.w};
      float va[4] = {vv.x, vv.y, vv.z, vv.w};
#pragma unroll
      for (int a = 0; a < 4; ++a)
#pragma unroll
        for (int e = 0; e < 4; ++e) acc[a][e] += xa[a] * va[e];
    }
#pragma unroll
    for (int a = 0; a < 4; ++a) {
      float4 o = {acc[a][0], acc[a][1], acc[a][2], acc[a][3]};
      *reinterpret_cast<float4*>(&Wb[(size_t)(d0 + a) * 128 + m0]) = o;
    }
  }
}

// ---------------- pass 2: prefix scan over chunks ----------------
__global__ __launch_bounds__(256) void k_memscanM(const float* __restrict__ W,
                                                  const float* __restrict__ ga,
                                                  float* __restrict__ Mp) {
  int bx = blockIdx.x;
  int bn = bx / 48, j = bx % 48;
  int elem = j * 256 + threadIdx.x;
  int b = bn >> 2, n = bn & 3;
  float M = 0.f;
  for (int ch = 0; ch < 32; ++ch) {
    size_t base = ((size_t)bn * 32 + ch) * 12288 + elem;
    Mp[base] = M;
    float g = ga[(b * 32 + ch) * NMEM + n];
    M = (1.f - g) * M + W[base];
  }
}

// ---------------- pass 3: reads = q @ M_prefix ----------------
__global__ __launch_bounds__(256) void k_memR(const float* __restrict__ q,
                                              const float* __restrict__ Mp,
                                              float* __restrict__ rd) {
  extern __shared__ float smem[];
  float* Q = smem;
  float* Ms = smem + 64 * 96;
  int bx = blockIdx.x;
  int bn = bx >> 5, ch = bx & 31;
  int b = bn >> 2, n = bn & 3;
  int t0 = b * SEQ + ch * 64;
  int tid = threadIdx.x;
  for (int i = tid; i < 64 * 96; i += 256) {
    int s = i / 96, d = i % 96;
    Q[i] = q[((size_t)(t0 + s) * NMEM + n) * HEADD + d];
  }
  for (int i = tid; i < 96 * 128; i += 256)
    Ms[i] = Mp[((size_t)bn * 32 + ch) * 12288 + i];
  __syncthreads();
  for (int t = tid; t < 512; t += 256) {
    int s0 = (t >> 5) * 4, m0 = (t & 31) * 4;
    float acc[4][4] = {};
    for (int k = 0; k < 96; ++k) {
      float4 mv = *reinterpret_cast<const float4*>(&Ms[k * 128 + m0]);
      float ma[4] = {mv.x, mv.y, mv.z, mv.w};
#pragma unroll
      for (int si = 0; si < 4; ++si) {
        float qs = Q[(s0 + si) * 96 + k];
#pragma unroll
        for (int mi = 0; mi < 4; ++mi) acc[si][mi] += qs * ma[mi];
      }
    }
#pragma unroll
    for (int si = 0; si < 4; ++si) {
      float4 o = {acc[si][0], acc[si][1], acc[si][2], acc[si][3]};
      *reinterpret_cast<float4*>(
          &rd[((size_t)(t0 + s0 + si) * NMEM + n) * MEMD + m0]) = o;
    }
  }
}

// ---------------- combine: out = (hconv + memproj) * head_weight ----------------
__global__ __launch_bounds__(256) void k_combine(
    const float* __restrict__ hconv, const float* __restrict__ reads,
    const float* __restrict__ Wout, const float* __restrict__ hw,
    float* __restrict__ outf, bf16* __restrict__ outb) {
  __shared__ float rd[NMEM * MEMD];
  int tok = blockIdx.x, tid = threadIdx.x;
  for (int i = tid; i < NMEM * MEMD; i += 256)
    rd[i] = reads[(size_t)tok * NMEM * MEMD + i];
  __syncthreads();
  for (int c = tid; c < HDIM; c += 256) {
    int head = c / HEADD, hd = c % HEADD;
    float v = hconv[(size_t)tok * HDIM + c];
    if (head >= 6 && head < 10) {
      int n = head - 6;
      const float* W = Wout + (size_t)(n * MEMD) * HEADD + hd;
      for (int m2 = 0; m2 < MEMD; ++m2) v += rd[n * MEMD + m2] * W[(size_t)m2 * HEADD];
    }
    v *= hw[tok * NHEADS + head];
    outf[(size_t)tok * HDIM + c] = v;
    outb[(size_t)tok * HDIM + c] = __float2bfloat16(v);
  }
}

extern "C" void kernel_launch(void* const* d_in, const int* in_sizes, int n_in,
                              void* d_out, int out_size, void* d_ws,
                              size_t ws_size, hipStream_t stream) {
  const float* x_in = (const float*)d_in[0];
  const float* norm1_w = (const float*)d_in[1];
  const float* norm2_w = (const float*)d_in[2];
  const float* norm3_w = (const float*)d_in[3];
  const float* cs_w = (const float*)d_in[4];
  const float* cs_b = (const float*)d_in[5];
  const float* cs_proj_w = (const float*)d_in[6];
  const float* cs_proj_b = (const float*)d_in[7];
  const float* gate_proj_w = (const float*)d_in[8];
  const float* router_w = (const float*)d_in[9];
  const float* router_b = (const float*)d_in[10];
  const float* head_w = (const float*)d_in[11];
  const float* head_b = (const float*)d_in[12];
  const float* mem_q = (const float*)d_in[13];
  const float* mem_k = (const float*)d_in[14];
  const float* mem_v = (const float*)d_in[15];
  const float* mem_gw = (const float*)d_in[16];
  const float* mem_gb = (const float*)d_in[17];
  const float* mem_out = (const float*)d_in[18];
  const float* mixgate_w = (const float*)d_in[19];
  const float* mixgate_b = (const float*)d_in[20];
  const float* mixing_w = (const float*)d_in[21];
  const float* mixing_b = (const float*)d_in[22];
  const float* ffn_in_w = (const float*)d_in[23];
  const float* ffn_out_w = (const float*)d_in[24];
  const float* cg_w = (const float*)d_in[25];
  const float* cg_b = (const float*)d_in[26];
  const float* sg_w = (const float*)d_in[27];
  const float* sg_b = (const float*)d_in[28];
  const float* fg_w = (const float*)d_in[29];
  const float* fg_b = (const float*)d_in[30];
  float* out = (float*)d_out;

  char* wsp = (char*)d_ws;
  size_t off = 0;
  auto alloc = [&](size_t bytes) -> char* {
    char* p = wsp + off;
    off += (bytes + 255) & ~(size_t)255;
    return p;
  };
  bf16* NB = (bf16*)alloc((size_t)TOKENS * HDIM * 2);
  float* F1 = (float*)alloc((size_t)TOKENS * HDIM * 4);
  float* F2 = (float*)alloc((size_t)TOKENS * HDIM * 4);
  float* F3 = (float*)alloc((size_t)TOKENS * HDIM * 4);
  char* REG = alloc((size_t)TOKENS * FINNER * 2);
  float* qb = (float*)REG;
  float* kgb = (float*)(REG + (size_t)TOKENS * 384 * 4);
  float* vb = (float*)((char*)kgb + (size_t)TOKENS * 384 * 4);
  float* rdb = (float*)((char*)vb + (size_t)TOKENS * 512 * 4);
  bf16* XG = (bf16*)REG;   // stage-C view
  bf16* NB2 = (bf16*)REG;  // mixgate output view (qb region dead by then)
  bf16* WTcs = (bf16*)alloc((size_t)1152 * 1152 * 2);
  bf16* WTgp = (bf16*)alloc((size_t)2304 * 1152 * 2);
  bf16* WTmg = (bf16*)alloc((size_t)1152 * 1152 * 2);
  bf16* WTmx = (bf16*)alloc((size_t)1152 * 1152 * 2);
  float* G1 = (float*)alloc(TOKENS * 4);
  float* G2 = (float*)alloc(TOKENS * 4);
  float* G3 = (float*)alloc(TOKENS * 4);
  float* GM = (float*)alloc((size_t)TOKENS * NMEM * 4);
  float* GA = (float*)alloc(4 * 32 * NMEM * 4);
  float* HW = (float*)alloc((size_t)TOKENS * NHEADS * 4);
  bf16* WTfin = (bf16*)F1;
  bf16* WTfout = (bf16*)F2;
  float* Wbuf = F2;
  float* Mpref = F3;

  const int gE = (TOKENS * HDIM) / 256;

  k_transpose_bf16<<<dim3(36, 36), 256, 0, stream>>>(cs_proj_w, WTcs, 1152, 1152);
  k_transpose_pair<<<dim3(72, 36), 256, 0, stream>>>(gate_proj_w, WTgp, 1152, 2304);
  k_transpose_bf16<<<dim3(36, 36), 256, 0, stream>>>(mixgate_w, WTmg, 1152, 1152);
  k_transpose_bf16<<<dim3(36, 36), 256, 0, stream>>>(mixing_w, WTmx, 1152, 1152);

  // ---- stage A: conv stack ----
  k_rms_gate<<<TOKENS, 256, 0, stream>>>(x_in, norm1_w, cg_w, cg_b, NB, F1, G1, 1,
                                         nullptr, nullptr, nullptr);
  k_convstack<<<1152, 256, 2 * CS_ROWS * 32 * 4, stream>>>(F1, NB, cs_w, cs_b);
  k_gemm<2><<<dim3(9, 64), 256, 0, stream>>>(NB, WTcs, cs_proj_b, G1, x_in, out,
                                             nullptr, TOKENS, 1152, 1152);

  // ---- stage B: multi-head state ----
  k_rms_gate<<<TOKENS, 256, 0, stream>>>(out, norm2_w, sg_w, sg_b, NB, nullptr, G2,
                                         0, router_w, router_b, HW);
  k_gemm<4><<<dim3(18, 64), 256, 0, stream>>>(NB, WTgp, nullptr, nullptr, nullptr,
                                              F3, nullptr, TOKENS, 2304, 1152);
  k_headconv<<<gE, 256, 0, stream>>>(F3, F1, head_w, head_b, 0);
  k_headconv<<<gE, 256, 0, stream>>>(F1, F2, head_w, head_b, 1);
  k_headconv<<<gE, 256, 0, stream>>>(F2, F1, head_w, head_b, 2);
  k_qkvg<<<TOKENS, 256, 0, stream>>>(F3, mem_q, mem_k, mem_v, mem_gw, mem_gb,
                                     qb, kgb, vb, GM);
  k_gmean<<<2, 256, 0, stream>>>(GM, GA);
  k_memW<<<512, 256, 0, stream>>>(kgb, vb, Wbuf);
  k_memscanM<<<768, 256, 0, stream>>>(Wbuf, GA, Mpref);
  k_memR<<<512, 256, (64 * 96 + 96 * 128) * 4, stream>>>(qb, Mpref, rdb);
  k_combine<<<TOKENS, 256, 0, stream>>>(F1, rdb, mem_out, HW, F2, NB);
  // fused mixgate: NB2 = bf16(F2 * sigm(NB@mixgate + b))
  k_gemm<6><<<dim3(9, 64), 256, 0, stream>>>(NB, WTmg, mixgate_b, nullptr, F2,
                                             nullptr, NB2, TOKENS, 1152, 1152);
  k_gemm<2><<<dim3(9, 64), 256, 0, stream>>>(NB2, WTmx, mixing_b, G2, out, out,
                                             nullptr, TOKENS, 1152, 1152);

  // ---- stage C: GLU FFN ----
  k_rms_gate<<<TOKENS, 256, 0, stream>>>(out, norm3_w, fg_w, fg_b, NB, nullptr, G3,
                                         0, nullptr, nullptr, nullptr);
  k_transpose_pair<<<dim3(288, 36), 256, 0, stream>>>(ffn_in_w, WTfin, 1152, 9216);
  k_transpose_bf16<<<dim3(36, 144), 256, 0, stream>>>(ffn_out_w, WTfout, 4608, 1152);
  k_gemm<5><<<dim3(72, 64), 256, 0, stream>>>(NB, WTfin, nullptr, nullptr, nullptr,
                                              nullptr, XG, TOKENS, 9216, 1152);
  k_gemm<2><<<dim3(9, 64), 256, 0, stream>>>(XG, WTfout, nullptr, G3, out, out,
                                             nullptr, TOKENS, 1152, 4608);
}

// Round 6
// 1583.712 us; speedup vs baseline: 1.6316x; 1.0645x over previous
//
#include <hip/hip_runtime.h>
#include <hip/hip_bf16.h>
#include <math.h>

#define TOKENS 8192
#define HDIM 1152
#define SEQ 2048
#define NHEADS 12
#define HEADD 96
#define NMEM 4
#define MEMD 128
#define FINNER 4608

typedef __hip_bfloat16 bf16;
typedef __attribute__((ext_vector_type(8))) short short8;
typedef __attribute__((ext_vector_type(4))) float floatx4;

__device__ __constant__ int g_hd_dil[NHEADS * 3] = {
    1, 2, 4,   1, 1, 1,    4, 8, 16,   8, 16, 32,
    32, 64, 128, 64, 128, 256, 256, 512, 1024, 1, 100, 200,
    1, 500, 1000, 1, 1024, 2048, 3, 9, 27, 5, 25, 125};

__device__ inline float sigm(float x) { return 1.0f / (1.0f + expf(-x)); }
__device__ inline float gelu_exact(float x) {
  return 0.5f * x * (1.0f + erff(x * 0.70710678118654752f));
}
__device__ inline float wred(float v) {
#pragma unroll
  for (int o = 32; o > 0; o >>= 1) v += __shfl_down(v, o);
  return v;
}
// async global->LDS, 16B per lane; LDS dest wave-uniform base + lane*16
__device__ inline void gl_lds16(const bf16* g, bf16* l) {
  __builtin_amdgcn_global_load_lds(
      (const __attribute__((address_space(1))) unsigned int*)g,
      (__attribute__((address_space(3))) unsigned int*)l, 16, 0, 0);
}

// ---------------- transpose f32 [K,N] -> bf16 [N,K] ----------------
__global__ __launch_bounds__(256) void k_transpose_bf16(
    const float* __restrict__ W, bf16* __restrict__ WT, int K, int N) {
  __shared__ float t[32][33];
  int k0 = blockIdx.y * 32, n0 = blockIdx.x * 32;
  int tx = threadIdx.x & 31, ty = threadIdx.x >> 5;
#pragma unroll
  for (int i = 0; i < 32; i += 8)
    t[ty + i][tx] = W[(size_t)(k0 + ty + i) * N + (n0 + tx)];
  __syncthreads();
#pragma unroll
  for (int i = 0; i < 32; i += 8)
    WT[(size_t)(n0 + ty + i) * K + (k0 + tx)] = __float2bfloat16(t[tx][ty + i]);
}

// ---- pair-permuted transpose: out row 2c = W[:,c], row 2c+1 = W[:,half+c] ----
__global__ __launch_bounds__(256) void k_transpose_pair(
    const float* __restrict__ W, bf16* __restrict__ WT, int K, int N) {
  __shared__ float t[32][33];
  int half = N >> 1;
  int k0 = blockIdx.y * 32, n0 = blockIdx.x * 32;
  int tx = threadIdx.x & 31, ty = threadIdx.x >> 5;
  int c = (tx < 16) ? (n0 / 2 + tx) : (half + n0 / 2 + tx - 16);
#pragma unroll
  for (int i = 0; i < 32; i += 8)
    t[ty + i][tx] = W[(size_t)(k0 + ty + i) * N + c];
  __syncthreads();
#pragma unroll
  for (int i = 0; i < 32; i += 8) {
    int r = ty + i;
    int cc = (r >> 1) + (r & 1) * 16;
    WT[(size_t)(n0 + r) * K + (k0 + tx)] = __float2bfloat16(t[tx][cc]);
  }
}

// ---------------- rmsnorm + scalar gate (+ optional fused router) ----------------
__global__ __launch_bounds__(256) void k_rms_gate(
    const float* __restrict__ x, const float* __restrict__ nw,
    const float* __restrict__ gw, const float* __restrict__ gb,
    bf16* __restrict__ outb, float* outf, float* __restrict__ gout,
    int writef, const float* __restrict__ rw, const float* __restrict__ rb,
    float* __restrict__ hwout) {
  __shared__ float r1[4], r2[4];
  __shared__ float rr[4][NHEADS];
  int tok = blockIdx.x;
  int tid = threadIdx.x;
  const float* row = x + (size_t)tok * HDIM;
  float a[5];
  float s2 = 0.f, gd = 0.f;
  for (int i = tid, k = 0; i < HDIM; i += 256, ++k) {
    float v = row[i];
    a[k] = v;
    s2 += v * v;
    gd += v * gw[i];
  }
  s2 = wred(s2);
  gd = wred(gd);
  int wave = tid >> 6, lane = tid & 63;
  if (lane == 0) {
    r1[wave] = s2;
    r2[wave] = gd;
  }
  __syncthreads();
  s2 = r1[0] + r1[1] + r1[2] + r1[3];
  gd = r2[0] + r2[1] + r2[2] + r2[3];
  float rn = 1.0f / sqrtf(s2 / (float)HDIM + 1e-6f);
  if (tid == 0) gout[tok] = sigm(gd + gb[0]);
  float racc[NHEADS] = {};
  for (int i = tid, k = 0; i < HDIM; i += 256, ++k) {
    float nv = a[k] * rn * nw[i];
    outb[(size_t)tok * HDIM + i] = __float2bfloat16(nv);
    if (writef) outf[(size_t)tok * HDIM + i] = nv;
    if (hwout) {
      const float* rp = &rw[(size_t)i * NHEADS];
#pragma unroll
      for (int o = 0; o < NHEADS; ++o) racc[o] += nv * rp[o];
    }
  }
  if (hwout) {
#pragma unroll
    for (int o = 0; o < NHEADS; ++o) racc[o] = wred(racc[o]);
    if (lane == 0)
#pragma unroll
      for (int o = 0; o < NHEADS; ++o) rr[wave][o] = racc[o];
    __syncthreads();
    if (tid < NHEADS) {
      float s = rr[0][tid] + rr[1][tid] + rr[2][tid] + rr[3][tid];
      hwout[(size_t)tok * NHEADS + tid] = sigm(s + rb[tid]);
    }
  }
}

// ---------------- fused conv stack: 6 dilated stages in LDS ----------------
#define CS_T 256
#define CS_HALO 189
#define CS_ROWS 445
__global__ __launch_bounds__(256) void k_convstack(
    const float* __restrict__ hin, bf16* __restrict__ outb,
    const float* __restrict__ cw, const float* __restrict__ cb) {
  extern __shared__ float lds[];
  float* cur = lds;
  float* nxt = lds + CS_ROWS * 32;
  int bx = blockIdx.x;
  int cs = bx % 36;
  int tile = (bx / 36) & 7;
  int b = bx / 288;
  int c0 = cs * 32;
  int S0 = tile * CS_T;
  int tid = threadIdx.x;
  int c = tid & 31;
  for (int i = tid; i < CS_ROWS * 32; i += 256) {
    int p = i >> 5, cc = i & 31;
    int sg = S0 - CS_HALO + p;
    cur[i] = (sg >= 0) ? hin[((size_t)(b * SEQ + sg)) * HDIM + c0 + cc] : 0.f;
  }
  const int dil[6] = {1, 2, 4, 8, 16, 32};
  const int Nk[6] = {3, 9, 21, 45, 93, 189};
#pragma unroll
  for (int k = 0; k < 6; ++k) {
    int d = dil[k];
    float w0 = cw[((size_t)k * HDIM + c0 + c) * 4 + 0];
    float w1 = cw[((size_t)k * HDIM + c0 + c) * 4 + 1];
    float w2 = cw[((size_t)k * HDIM + c0 + c) * 4 + 2];
    float w3 = cw[((size_t)k * HDIM + c0 + c) * 4 + 3];
    float bb = cb[(size_t)k * HDIM + c0 + c];
    __syncthreads();
    for (int p = Nk[k] + (tid >> 5); p < CS_ROWS; p += 8) {
      int i = p * 32 + c;
      int sg = S0 - CS_HALO + p;
      float acc = bb + w0 * cur[i - 3 * d * 32] + w1 * cur[i - 2 * d * 32] +
                  w2 * cur[i - d * 32] + w3 * cur[i];
      nxt[i] = (sg >= 0) ? (cur[i] + gelu_exact(acc)) : 0.f;
    }
    float* t = cur;
    cur = nxt;
    nxt = t;
  }
  __syncthreads();
  for (int r = tid >> 5; r < CS_T; r += 8) {
    outb[((size_t)(b * SEQ + S0 + r)) * HDIM + c0 + c] =
        __float2bfloat16(cur[(CS_HALO + r) * 32 + c]);
  }
}

// ---------------- per-head conv step j: h = h + dconv(h) ----------------
__global__ __launch_bounds__(256) void k_headconv(
    const float* __restrict__ hin, float* __restrict__ hout,
    const float* __restrict__ hw_, const float* __restrict__ hb_, int j) {
  size_t idx = (size_t)blockIdx.x * 256 + threadIdx.x;
  if (idx >= (size_t)TOKENS * HDIM) return;
  int c = (int)(idx % HDIM);
  int head = c / HEADD, hd = c % HEADD;
  size_t tok = idx / HDIM;
  int s = (int)(tok % SEQ);
  int d = g_hd_dil[head * 3 + j];
  const float* w = hw_ + ((size_t)(head * 3 + j) * HEADD + hd) * 4;
  float acc = hb_[(head * 3 + j) * HEADD + hd];
#pragma unroll
  for (int jj = 0; jj < 4; ++jj) {
    int back = (3 - jj) * d;
    if (s - back >= 0) acc += w[jj] * hin[idx - (size_t)back * HDIM];
  }
  hout[idx] = hin[idx] + acc;
}

// ---------------- GEMM: BK=64, global_load_lds staging, swizzled LDS ----------
// C[M,N] = A[M,K](bf16) * BT[N,K](bf16)^T.  18 K-iters for K=1152.
// LDS row = 64 bf16 = 128 B = 8 chunks of 16B. Slot s of row r holds global
// k-chunk (s - r) & 7; fragment read uses slot (c + r) & 7 -> 2-way bank
// aliasing only (free). Staging lane fetches its permuted chunk so the DMA's
// lane-linear LDS write lands chunks in swizzled slots.
// MODE 2: out = addin + gate[m]*(acc+bias)
// MODE 4: pair-GLU -> a*sigm(g) f32 (N halves)
// MODE 5: pair-GLU -> bf16 (N halves)
// MODE 6: outb = bf16(addin * sigm(acc+bias))
template <int MODE>
__global__ __launch_bounds__(256) void k_gemm(
    const bf16* __restrict__ A, const bf16* __restrict__ BT,
    const float* __restrict__ bias, const float* __restrict__ gate,
    const float* addin, float* outf, bf16* outb, int M, int N, int K) {
  __shared__ bf16 As[128 * 64];
  __shared__ bf16 Bs[128 * 64];
  const int tid = threadIdx.x;
  const int m0 = blockIdx.y * 128, n0 = blockIdx.x * 128;
  const int wave = tid >> 6, lane = tid & 63;
  const int wm = (wave & 1) * 64, wn = (wave >> 1) * 64;
  const int l16 = lane & 15, kq = lane >> 4;
  // staging: wave fills rows [wave*32, wave*32+32); one gl_lds16 covers 8 rows
  const int srow = lane >> 3;                   // row within 8-row group
  const int schunk = ((lane & 7) - srow) & 7;   // global chunk for this slot
  const bf16* gA = A + (size_t)(m0 + wave * 32 + srow) * K + schunk * 8;
  const bf16* gB = BT + (size_t)(n0 + wave * 32 + srow) * K + schunk * 8;
  bf16* lA = &As[wave * 32 * 64];
  bf16* lB = &Bs[wave * 32 * 64];
  const size_t rstride = (size_t)8 * K;
  // fragment-read swizzled columns for the two k-phases (per-lane constant part)
  const int col0 = ((kq + l16) & 7) * 8;
  const int col1 = ((kq + 4 + l16) & 7) * 8;
  floatx4 acc[4][4];
  floatx4 zero = {0.f, 0.f, 0.f, 0.f};
#pragma unroll
  for (int i = 0; i < 4; ++i)
#pragma unroll
    for (int jj = 0; jj < 4; ++jj) acc[i][jj] = zero;

  for (int k0 = 0; k0 < K; k0 += 64) {
    __syncthreads();
#pragma unroll
    for (int i = 0; i < 4; ++i) {
      gl_lds16(gA + k0 + i * rstride, lA + i * 8 * 64);
      gl_lds16(gB + k0 + i * rstride, lB + i * 8 * 64);
    }
    __syncthreads();
#pragma unroll
    for (int ks = 0; ks < 2; ++ks) {
      const int col = ks ? col1 : col0;
      short8 af[4], bfr[4];
#pragma unroll
      for (int t = 0; t < 4; ++t) {
        af[t] = *reinterpret_cast<const short8*>(&As[(wm + t * 16 + l16) * 64 + col]);
        bfr[t] = *reinterpret_cast<const short8*>(&Bs[(wn + t * 16 + l16) * 64 + col]);
      }
#pragma unroll
      for (int mt = 0; mt < 4; ++mt)
#pragma unroll
        for (int nt = 0; nt < 4; ++nt)
          acc[mt][nt] = __builtin_amdgcn_mfma_f32_16x16x32_bf16(
              af[mt], bfr[nt], acc[mt][nt], 0, 0, 0);
    }
  }

  if (MODE == 4 || MODE == 5) {
    const int halfN = N >> 1;
#pragma unroll
    for (int mt = 0; mt < 4; ++mt) {
#pragma unroll
      for (int nt = 0; nt < 4; ++nt) {
        int nn = n0 + wn + nt * 16 + l16;
#pragma unroll
        for (int r = 0; r < 4; ++r) {
          float v = acc[mt][nt][r];
          float g = __shfl_xor(v, 1);
          if ((lane & 1) == 0) {
            int m = m0 + wm + mt * 16 + kq * 4 + r;
            float res = v * sigm(g);
            size_t o = (size_t)m * halfN + (nn >> 1);
            if (MODE == 4) outf[o] = res;
            else outb[o] = __float2bfloat16(res);
          }
        }
      }
    }
    return;
  }

#pragma unroll
  for (int mt = 0; mt < 4; ++mt) {
#pragma unroll
    for (int nt = 0; nt < 4; ++nt) {
      int n = n0 + wn + nt * 16 + l16;
      float bv = bias ? bias[n] : 0.f;
#pragma unroll
      for (int r = 0; r < 4; ++r) {
        int m = m0 + wm + mt * 16 + kq * 4 + r;
        float v = acc[mt][nt][r] + bv;
        size_t o = (size_t)m * N + n;
        if (MODE == 2) outf[o] = addin[o] + gate[m] * v;
        else if (MODE == 6) outb[o] = __float2bfloat16(addin[o] * sigm(v));
      }
    }
  }
}

// ---------------- memory q/kg/v/g projections ----------------
__global__ __launch_bounds__(256) void k_qkvg(
    const float* __restrict__ xh, const float* __restrict__ Wq,
    const float* __restrict__ Wk, const float* __restrict__ Wv,
    const float* __restrict__ gw, const float* __restrict__ gb,
    float* __restrict__ q, float* __restrict__ kg, float* __restrict__ v,
    float* __restrict__ gout) {
  __shared__ float xm[NMEM * HEADD];
  __shared__ float gsh[NMEM];
  int tok = blockIdx.x, tid = threadIdx.x;
  for (int i = tid; i < NMEM * HEADD; i += 256)
    xm[i] = xh[(size_t)tok * HDIM + 6 * HEADD + i];
  __syncthreads();
  if (tid < NMEM) {
    float a = gb[tid];
    for (int d = 0; d < HEADD; ++d) a += xm[tid * HEADD + d] * gw[tid * HEADD + d];
    float s = sigm(a);
    gsh[tid] = s;
    gout[tok * NMEM + tid] = s;
  }
  __syncthreads();
  for (int i = tid; i < 1280; i += 256) {
    if (i < 384) {
      int n = i / HEADD, e = i % HEADD;
      const float* W = Wq + (size_t)n * HEADD * HEADD + e;
      const float* xr = xm + n * HEADD;
      float a = 0.f;
      for (int d = 0; d < HEADD; ++d) a += xr[d] * W[(size_t)d * HEADD];
      q[(size_t)tok * 384 + i] = a;
    } else if (i < 768) {
      int i2 = i - 384;
      int n = i2 / HEADD, e = i2 % HEADD;
      const float* W = Wk + (size_t)n * HEADD * HEADD + e;
      const float* xr = xm + n * HEADD;
      float a = 0.f;
      for (int d = 0; d < HEADD; ++d) a += xr[d] * W[(size_t)d * HEADD];
      kg[(size_t)tok * 384 + i2] = a * gsh[n];
    } else {
      int i2 = i - 768;
      int n = i2 / MEMD, e = i2 % MEMD;
      const float* W = Wv + (size_t)n * HEADD * MEMD + e;
      const float* xr = xm + n * HEADD;
      float a = 0.f;
      for (int d = 0; d < HEADD; ++d) a += xr[d] * W[(size_t)d * MEMD];
      v[(size_t)tok * 512 + i2] = a;
    }
  }
}

// ---------------- chunk means of g ----------------
__global__ __launch_bounds__(256) void k_gmean(const float* __restrict__ g,
                                               float* __restrict__ ga) {
  int idx = blockIdx.x * 256 + threadIdx.x;
  if (idx >= 512) return;
  int b = idx >> 7, ch = (idx >> 2) & 31, n = idx & 3;
  float s = 0.f;
  for (int t = 0; t < 64; ++t)
    s += g[((size_t)b * SEQ + ch * 64 + t) * NMEM + n];
  ga[idx] = s * (1.0f / 64.0f);
}

// ---------------- pass 1: per-chunk writes W[bnc][96][128] ----------------
__global__ __launch_bounds__(256) void k_memW(const float* __restrict__ kg,
                                              const float* __restrict__ v,
                                              float* __restrict__ W) {
  __shared__ float X[64 * 96];
  __shared__ float V[64 * 128];
  int bx = blockIdx.x;
  int bn = bx >> 5, ch = bx & 31;
  int b = bn >> 2, n = bn & 3;
  int t0 = b * SEQ + ch * 64;
  int tid = threadIdx.x;
  for (int i = tid; i < 64 * 96; i += 256) {
    int s = i / 96, d = i % 96;
    X[i] = kg[((size_t)(t0 + s) * NMEM + n) * HEADD + d];
  }
  for (int i = tid; i < 64 * 128; i += 256) {
    int s = i >> 7, m = i & 127;
    V[i] = v[((size_t)(t0 + s) * NMEM + n) * MEMD + m];
  }
  __syncthreads();
  float* Wb = W + (size_t)bx * 96 * 128;
  for (int t = tid; t < 768; t += 256) {
    int d0 = (t >> 5) * 4, m0 = (t & 31) * 4;
    float acc[4][4] = {};
    for (int s = 0; s < 64; ++s) {
      float4 xv = *reinterpret_cast<const float4*>(&X[s * 96 + d0]);
      float4 vv = *reinterpret_cast<const float4*>(&V[s * 128 + m0]);
      float xa[4] = {xv.x, xv.y, xv.z, xv.w};
      float va[4] = {vv.x, vv.y, vv.z, vv.w};
#pragma unroll
      for (int a = 0; a < 4; ++a)
#pragma unroll
        for (int e = 0; e < 4; ++e) acc[a][e] += xa[a] * va[e];
    }
#pragma unroll
    for (int a = 0; a < 4; ++a) {
      float4 o = {acc[a][0], acc[a][1], acc[a][2], acc[a][3]};
      *reinterpret_cast<float4*>(&Wb[(size_t)(d0 + a) * 128 + m0]) = o;
    }
  }
}

// ---------------- pass 2: prefix scan over chunks ----------------
__global__ __launch_bounds__(256) void k_memscanM(const float* __restrict__ W,
                                                  const float* __restrict__ ga,
                                                  float* __restrict__ Mp) {
  int bx = blockIdx.x;
  int bn = bx / 48, j = bx % 48;
  int elem = j * 256 + threadIdx.x;
  int b = bn >> 2, n = bn & 3;
  float M = 0.f;
  for (int ch = 0; ch < 32; ++ch) {
    size_t base = ((size_t)bn * 32 + ch) * 12288 + elem;
    Mp[base] = M;
    float g = ga[(b * 32 + ch) * NMEM + n];
    M = (1.f - g) * M + W[base];
  }
}

// ---------------- pass 3: reads = q @ M_prefix ----------------
__global__ __launch_bounds__(256) void k_memR(const float* __restrict__ q,
                                              const float* __restrict__ Mp,
                                              float* __restrict__ rd) {
  extern __shared__ float smem[];
  float* Q = smem;
  float* Ms = smem + 64 * 96;
  int bx = blockIdx.x;
  int bn = bx >> 5, ch = bx & 31;
  int b = bn >> 2, n = bn & 3;
  int t0 = b * SEQ + ch * 64;
  int tid = threadIdx.x;
  for (int i = tid; i < 64 * 96; i += 256) {
    int s = i / 96, d = i % 96;
    Q[i] = q[((size_t)(t0 + s) * NMEM + n) * HEADD + d];
  }
  for (int i = tid; i < 96 * 128; i += 256)
    Ms[i] = Mp[((size_t)bn * 32 + ch) * 12288 + i];
  __syncthreads();
  for (int t = tid; t < 512; t += 256) {
    int s0 = (t >> 5) * 4, m0 = (t & 31) * 4;
    float acc[4][4] = {};
    for (int k = 0; k < 96; ++k) {
      float4 mv = *reinterpret_cast<const float4*>(&Ms[k * 128 + m0]);
      float ma[4] = {mv.x, mv.y, mv.z, mv.w};
#pragma unroll
      for (int si = 0; si < 4; ++si) {
        float qs = Q[(s0 + si) * 96 + k];
#pragma unroll
        for (int mi = 0; mi < 4; ++mi) acc[si][mi] += qs * ma[mi];
      }
    }
#pragma unroll
    for (int si = 0; si < 4; ++si) {
      float4 o = {acc[si][0], acc[si][1], acc[si][2], acc[si][3]};
      *reinterpret_cast<float4*>(
          &rd[((size_t)(t0 + s0 + si) * NMEM + n) * MEMD + m0]) = o;
    }
  }
}

// ---------------- combine: out = (hconv + memproj) * head_weight ----------------
__global__ __launch_bounds__(256) void k_combine(
    const float* __restrict__ hconv, const float* __restrict__ reads,
    const float* __restrict__ Wout, const float* __restrict__ hw,
    float* __restrict__ outf, bf16* __restrict__ outb) {
  __shared__ float rd[NMEM * MEMD];
  int tok = blockIdx.x, tid = threadIdx.x;
  for (int i = tid; i < NMEM * MEMD; i += 256)
    rd[i] = reads[(size_t)tok * NMEM * MEMD + i];
  __syncthreads();
  for (int c = tid; c < HDIM; c += 256) {
    int head = c / HEADD, hd = c % HEADD;
    float v = hconv[(size_t)tok * HDIM + c];
    if (head >= 6 && head < 10) {
      int n = head - 6;
      const float* W = Wout + (size_t)(n * MEMD) * HEADD + hd;
      for (int m2 = 0; m2 < MEMD; ++m2) v += rd[n * MEMD + m2] * W[(size_t)m2 * HEADD];
    }
    v *= hw[tok * NHEADS + head];
    outf[(size_t)tok * HDIM + c] = v;
    outb[(size_t)tok * HDIM + c] = __float2bfloat16(v);
  }
}

extern "C" void kernel_launch(void* const* d_in, const int* in_sizes, int n_in,
                              void* d_out, int out_size, void* d_ws,
                              size_t ws_size, hipStream_t stream) {
  const float* x_in = (const float*)d_in[0];
  const float* norm1_w = (const float*)d_in[1];
  const float* norm2_w = (const float*)d_in[2];
  const float* norm3_w = (const float*)d_in[3];
  const float* cs_w = (const float*)d_in[4];
  const float* cs_b = (const float*)d_in[5];
  const float* cs_proj_w = (const float*)d_in[6];
  const float* cs_proj_b = (const float*)d_in[7];
  const float* gate_proj_w = (const float*)d_in[8];
  const float* router_w = (const float*)d_in[9];
  const float* router_b = (const float*)d_in[10];
  const float* head_w = (const float*)d_in[11];
  const float* head_b = (const float*)d_in[12];
  const float* mem_q = (const float*)d_in[13];
  const float* mem_k = (const float*)d_in[14];
  const float* mem_v = (const float*)d_in[15];
  const float* mem_gw = (const float*)d_in[16];
  const float* mem_gb = (const float*)d_in[17];
  const float* mem_out = (const float*)d_in[18];
  const float* mixgate_w = (const float*)d_in[19];
  const float* mixgate_b = (const float*)d_in[20];
  const float* mixing_w = (const float*)d_in[21];
  const float* mixing_b = (const float*)d_in[22];
  const float* ffn_in_w = (const float*)d_in[23];
  const float* ffn_out_w = (const float*)d_in[24];
  const float* cg_w = (const float*)d_in[25];
  const float* cg_b = (const float*)d_in[26];
  const float* sg_w = (const float*)d_in[27];
  const float* sg_b = (const float*)d_in[28];
  const float* fg_w = (const float*)d_in[29];
  const float* fg_b = (const float*)d_in[30];
  float* out = (float*)d_out;

  char* wsp = (char*)d_ws;
  size_t off = 0;
  auto alloc = [&](size_t bytes) -> char* {
    char* p = wsp + off;
    off += (bytes + 255) & ~(size_t)255;
    return p;
  };
  bf16* NB = (bf16*)alloc((size_t)TOKENS * HDIM * 2);
  float* F1 = (float*)alloc((size_t)TOKENS * HDIM * 4);
  float* F2 = (float*)alloc((size_t)TOKENS * HDIM * 4);
  float* F3 = (float*)alloc((size_t)TOKENS * HDIM * 4);
  char* REG = alloc((size_t)TOKENS * FINNER * 2);
  float* qb = (float*)REG;
  float* kgb = (float*)(REG + (size_t)TOKENS * 384 * 4);
  float* vb = (float*)((char*)kgb + (size_t)TOKENS * 384 * 4);
  float* rdb = (float*)((char*)vb + (size_t)TOKENS * 512 * 4);
  bf16* XG = (bf16*)REG;   // stage-C view
  bf16* NB2 = (bf16*)REG;  // mixgate output view (qb region dead by then)
  bf16* WTcs = (bf16*)alloc((size_t)1152 * 1152 * 2);
  bf16* WTgp = (bf16*)alloc((size_t)2304 * 1152 * 2);
  bf16* WTmg = (bf16*)alloc((size_t)1152 * 1152 * 2);
  bf16* WTmx = (bf16*)alloc((size_t)1152 * 1152 * 2);
  float* G1 = (float*)alloc(TOKENS * 4);
  float* G2 = (float*)alloc(TOKENS * 4);
  float* G3 = (float*)alloc(TOKENS * 4);
  float* GM = (float*)alloc((size_t)TOKENS * NMEM * 4);
  float* GA = (float*)alloc(4 * 32 * NMEM * 4);
  float* HW = (float*)alloc((size_t)TOKENS * NHEADS * 4);
  bf16* WTfin = (bf16*)F1;
  bf16* WTfout = (bf16*)F2;
  float* Wbuf = F2;
  float* Mpref = F3;

  const int gE = (TOKENS * HDIM) / 256;

  k_transpose_bf16<<<dim3(36, 36), 256, 0, stream>>>(cs_proj_w, WTcs, 1152, 1152);
  k_transpose_pair<<<dim3(72, 36), 256, 0, stream>>>(gate_proj_w, WTgp, 1152, 2304);
  k_transpose_bf16<<<dim3(36, 36), 256, 0, stream>>>(mixgate_w, WTmg, 1152, 1152);
  k_transpose_bf16<<<dim3(36, 36), 256, 0, stream>>>(mixing_w, WTmx, 1152, 1152);

  // ---- stage A: conv stack ----
  k_rms_gate<<<TOKENS, 256, 0, stream>>>(x_in, norm1_w, cg_w, cg_b, NB, F1, G1, 1,
                                         nullptr, nullptr, nullptr);
  k_convstack<<<1152, 256, 2 * CS_ROWS * 32 * 4, stream>>>(F1, NB, cs_w, cs_b);
  k_gemm<2><<<dim3(9, 64), 256, 0, stream>>>(NB, WTcs, cs_proj_b, G1, x_in, out,
                                             nullptr, TOKENS, 1152, 1152);

  // ---- stage B: multi-head state ----
  k_rms_gate<<<TOKENS, 256, 0, stream>>>(out, norm2_w, sg_w, sg_b, NB, nullptr, G2,
                                         0, router_w, router_b, HW);
  k_gemm<4><<<dim3(18, 64), 256, 0, stream>>>(NB, WTgp, nullptr, nullptr, nullptr,
                                              F3, nullptr, TOKENS, 2304, 1152);
  k_headconv<<<gE, 256, 0, stream>>>(F3, F1, head_w, head_b, 0);
  k_headconv<<<gE, 256, 0, stream>>>(F1, F2, head_w, head_b, 1);
  k_headconv<<<gE, 256, 0, stream>>>(F2, F1, head_w, head_b, 2);
  k_qkvg<<<TOKENS, 256, 0, stream>>>(F3, mem_q, mem_k, mem_v, mem_gw, mem_gb,
                                     qb, kgb, vb, GM);
  k_gmean<<<2, 256, 0, stream>>>(GM, GA);
  k_memW<<<512, 256, 0, stream>>>(kgb, vb, Wbuf);
  k_memscanM<<<768, 256, 0, stream>>>(Wbuf, GA, Mpref);
  k_memR<<<512, 256, (64 * 96 + 96 * 128) * 4, stream>>>(qb, Mpref, rdb);
  k_combine<<<TOKENS, 256, 0, stream>>>(F1, rdb, mem_out, HW, F2, NB);
  // fused mixgate: NB2 = bf16(F2 * sigm(NB@mixgate + b))
  k_gemm<6><<<dim3(9, 64), 256, 0, stream>>>(NB, WTmg, mixgate_b, nullptr, F2,
                                             nullptr, NB2, TOKENS, 1152, 1152);
  k_gemm<2><<<dim3(9, 64), 256, 0, stream>>>(NB2, WTmx, mixing_b, G2, out, out,
                                             nullptr, TOKENS, 1152, 1152);

  // ---- stage C: GLU FFN ----
  k_rms_gate<<<TOKENS, 256, 0, stream>>>(out, norm3_w, fg_w, fg_b, NB, nullptr, G3,
                                         0, nullptr, nullptr, nullptr);
  k_transpose_pair<<<dim3(288, 36), 256, 0, stream>>>(ffn_in_w, WTfin, 1152, 9216);
  k_transpose_bf16<<<dim3(36, 144), 256, 0, stream>>>(ffn_out_w, WTfout, 4608, 1152);
  k_gemm<5><<<dim3(72, 64), 256, 0, stream>>>(NB, WTfin, nullptr, nullptr, nullptr,
                                              nullptr, XG, TOKENS, 9216, 1152);
  k_gemm<2><<<dim3(9, 64), 256, 0, stream>>>(XG, WTfout, nullptr, G3, out, out,
                                             nullptr, TOKENS, 1152, 4608);
}

// Round 7
// 1399.538 us; speedup vs baseline: 1.8463x; 1.1316x over previous
//
#include <hip/hip_runtime.h>
#include <hip/hip_bf16.h>
#include <math.h>

#define TOKENS 8192
#define HDIM 1152
#define SEQ 2048
#define NHEADS 12
#define HEADD 96
#define NMEM 4
#define MEMD 128
#define FINNER 4608

typedef __hip_bfloat16 bf16;
typedef __attribute__((ext_vector_type(8))) short short8;
typedef __attribute__((ext_vector_type(4))) float floatx4;

__device__ __constant__ int g_hd_dil[NHEADS * 3] = {
    1, 2, 4,   1, 1, 1,    4, 8, 16,   8, 16, 32,
    32, 64, 128, 64, 128, 256, 256, 512, 1024, 1, 100, 200,
    1, 500, 1000, 1, 1024, 2048, 3, 9, 27, 5, 25, 125};

__device__ inline float sigm(float x) { return 1.0f / (1.0f + expf(-x)); }
__device__ inline float gelu_exact(float x) {
  return 0.5f * x * (1.0f + erff(x * 0.70710678118654752f));
}
__device__ inline float wred(float v) {
#pragma unroll
  for (int o = 32; o > 0; o >>= 1) v += __shfl_down(v, o);
  return v;
}
// async global->LDS, 16B per lane; LDS dest wave-uniform base + lane*16
__device__ inline void gl_lds16(const bf16* g, bf16* l) {
  __builtin_amdgcn_global_load_lds(
      (const __attribute__((address_space(1))) unsigned int*)g,
      (__attribute__((address_space(3))) unsigned int*)l, 16, 0, 0);
}

// ---------------- transpose f32 [K,N] -> bf16 [N,K] ----------------
__global__ __launch_bounds__(256) void k_transpose_bf16(
    const float* __restrict__ W, bf16* __restrict__ WT, int K, int N) {
  __shared__ float t[32][33];
  int k0 = blockIdx.y * 32, n0 = blockIdx.x * 32;
  int tx = threadIdx.x & 31, ty = threadIdx.x >> 5;
#pragma unroll
  for (int i = 0; i < 32; i += 8)
    t[ty + i][tx] = W[(size_t)(k0 + ty + i) * N + (n0 + tx)];
  __syncthreads();
#pragma unroll
  for (int i = 0; i < 32; i += 8)
    WT[(size_t)(n0 + ty + i) * K + (k0 + tx)] = __float2bfloat16(t[tx][ty + i]);
}

// ---- pair-permuted transpose: out row 2c = W[:,c], row 2c+1 = W[:,half+c] ----
__global__ __launch_bounds__(256) void k_transpose_pair(
    const float* __restrict__ W, bf16* __restrict__ WT, int K, int N) {
  __shared__ float t[32][33];
  int half = N >> 1;
  int k0 = blockIdx.y * 32, n0 = blockIdx.x * 32;
  int tx = threadIdx.x & 31, ty = threadIdx.x >> 5;
  int c = (tx < 16) ? (n0 / 2 + tx) : (half + n0 / 2 + tx - 16);
#pragma unroll
  for (int i = 0; i < 32; i += 8)
    t[ty + i][tx] = W[(size_t)(k0 + ty + i) * N + c];
  __syncthreads();
#pragma unroll
  for (int i = 0; i < 32; i += 8) {
    int r = ty + i;
    int cc = (r >> 1) + (r & 1) * 16;
    WT[(size_t)(n0 + r) * K + (k0 + tx)] = __float2bfloat16(t[tx][cc]);
  }
}

// ---------------- rmsnorm + scalar gate (+ optional fused router) ----------------
__global__ __launch_bounds__(256) void k_rms_gate(
    const float* __restrict__ x, const float* __restrict__ nw,
    const float* __restrict__ gw, const float* __restrict__ gb,
    bf16* __restrict__ outb, float* outf, float* __restrict__ gout,
    int writef, const float* __restrict__ rw, const float* __restrict__ rb,
    float* __restrict__ hwout) {
  __shared__ float r1[4], r2[4];
  __shared__ float rr[4][NHEADS];
  int tok = blockIdx.x;
  int tid = threadIdx.x;
  const float* row = x + (size_t)tok * HDIM;
  float a[5];
  float s2 = 0.f, gd = 0.f;
  for (int i = tid, k = 0; i < HDIM; i += 256, ++k) {
    float v = row[i];
    a[k] = v;
    s2 += v * v;
    gd += v * gw[i];
  }
  s2 = wred(s2);
  gd = wred(gd);
  int wave = tid >> 6, lane = tid & 63;
  if (lane == 0) {
    r1[wave] = s2;
    r2[wave] = gd;
  }
  __syncthreads();
  s2 = r1[0] + r1[1] + r1[2] + r1[3];
  gd = r2[0] + r2[1] + r2[2] + r2[3];
  float rn = 1.0f / sqrtf(s2 / (float)HDIM + 1e-6f);
  if (tid == 0) gout[tok] = sigm(gd + gb[0]);
  float racc[NHEADS] = {};
  for (int i = tid, k = 0; i < HDIM; i += 256, ++k) {
    float nv = a[k] * rn * nw[i];
    outb[(size_t)tok * HDIM + i] = __float2bfloat16(nv);
    if (writef) outf[(size_t)tok * HDIM + i] = nv;
    if (hwout) {
      const float* rp = &rw[(size_t)i * NHEADS];
#pragma unroll
      for (int o = 0; o < NHEADS; ++o) racc[o] += nv * rp[o];
    }
  }
  if (hwout) {
#pragma unroll
    for (int o = 0; o < NHEADS; ++o) racc[o] = wred(racc[o]);
    if (lane == 0)
#pragma unroll
      for (int o = 0; o < NHEADS; ++o) rr[wave][o] = racc[o];
    __syncthreads();
    if (tid < NHEADS) {
      float s = rr[0][tid] + rr[1][tid] + rr[2][tid] + rr[3][tid];
      hwout[(size_t)tok * NHEADS + tid] = sigm(s + rb[tid]);
    }
  }
}

// ---------------- fused conv stack: 6 stages, single LDS buffer ----------------
// block = (batch, 256-token tile, 16-ch slice); 28.5 KB LDS -> 5 blocks/CU.
// Per stage: compute new values into registers, barrier, write back in place.
// Rows < Nk[k] keep stale values but are never read by later stages.
#define CS_T 256
#define CS_HALO 189
#define CS_ROWS 445
#define CS_J 28
__global__ __launch_bounds__(256) void k_convstack(
    const bf16* __restrict__ hin, bf16* __restrict__ outb,
    const float* __restrict__ cw, const float* __restrict__ cb) {
  __shared__ float cur[CS_ROWS * 16];
  int bx = blockIdx.x;
  int cs = bx % 72;
  int tile = (bx / 72) & 7;
  int b = bx / 576;
  int c0 = cs * 16;
  int S0 = tile * CS_T;
  int tid = threadIdx.x;
  int c = tid & 15, pg = tid >> 4;
  for (int i = tid; i < CS_ROWS * 16; i += 256) {
    int p = i >> 4, cc = i & 15;
    int sg = S0 - CS_HALO + p;
    cur[i] = (sg >= 0)
                 ? __bfloat162float(hin[((size_t)(b * SEQ + sg)) * HDIM + c0 + cc])
                 : 0.f;
  }
  const int dil[6] = {1, 2, 4, 8, 16, 32};
  const int Nk[6] = {3, 9, 21, 45, 93, 189};
  float nv[CS_J];
#pragma unroll
  for (int k = 0; k < 6; ++k) {
    int d = dil[k];
    float w0 = cw[((size_t)k * HDIM + c0 + c) * 4 + 0];
    float w1 = cw[((size_t)k * HDIM + c0 + c) * 4 + 1];
    float w2 = cw[((size_t)k * HDIM + c0 + c) * 4 + 2];
    float w3 = cw[((size_t)k * HDIM + c0 + c) * 4 + 3];
    float bb = cb[(size_t)k * HDIM + c0 + c];
    __syncthreads();
#pragma unroll
    for (int j = 0; j < CS_J; ++j) {
      int p = pg + 16 * j;
      if (p >= Nk[k] && p < CS_ROWS) {
        int i = p * 16 + c;
        float acc = bb + w0 * cur[i - 3 * d * 16] + w1 * cur[i - 2 * d * 16] +
                    w2 * cur[i - d * 16] + w3 * cur[i];
        int sg = S0 - CS_HALO + p;
        nv[j] = (sg >= 0) ? (cur[i] + gelu_exact(acc)) : 0.f;
      }
    }
    __syncthreads();
#pragma unroll
    for (int j = 0; j < CS_J; ++j) {
      int p = pg + 16 * j;
      if (p >= Nk[k] && p < CS_ROWS) cur[p * 16 + c] = nv[j];
    }
  }
  __syncthreads();
  for (int r = pg; r < CS_T; r += 16) {
    outb[((size_t)(b * SEQ + S0 + r)) * HDIM + c0 + c] =
        __float2bfloat16(cur[(CS_HALO + r) * 16 + c]);
  }
}

// ---------------- per-head conv step j: h = h + dconv(h) ----------------
__global__ __launch_bounds__(256) void k_headconv(
    const float* __restrict__ hin, float* __restrict__ hout,
    const float* __restrict__ hw_, const float* __restrict__ hb_, int j) {
  size_t idx = (size_t)blockIdx.x * 256 + threadIdx.x;
  if (idx >= (size_t)TOKENS * HDIM) return;
  int c = (int)(idx % HDIM);
  int head = c / HEADD, hd = c % HEADD;
  size_t tok = idx / HDIM;
  int s = (int)(tok % SEQ);
  int d = g_hd_dil[head * 3 + j];
  const float* w = hw_ + ((size_t)(head * 3 + j) * HEADD + hd) * 4;
  float acc = hb_[(head * 3 + j) * HEADD + hd];
#pragma unroll
  for (int jj = 0; jj < 4; ++jj) {
    int back = (3 - jj) * d;
    if (s - back >= 0) acc += w[jj] * hin[idx - (size_t)back * HDIM];
  }
  hout[idx] = hin[idx] + acc;
}

// ---------------- GEMM: BK=64, global_load_lds staging, swizzled LDS ----------
// MODE 2: out = addin + gate[m]*(acc+bias)
// MODE 4: pair-GLU -> a*sigm(g) f32 (N halves)
// MODE 5: pair-GLU -> bf16 (N halves)
// MODE 6: outb = bf16(addin * sigm(acc+bias))
template <int MODE>
__global__ __launch_bounds__(256) void k_gemm(
    const bf16* __restrict__ A, const bf16* __restrict__ BT,
    const float* __restrict__ bias, const float* __restrict__ gate,
    const float* addin, float* outf, bf16* outb, int M, int N, int K) {
  __shared__ bf16 As[128 * 64];
  __shared__ bf16 Bs[128 * 64];
  const int tid = threadIdx.x;
  const int m0 = blockIdx.y * 128, n0 = blockIdx.x * 128;
  const int wave = tid >> 6, lane = tid & 63;
  const int wm = (wave & 1) * 64, wn = (wave >> 1) * 64;
  const int l16 = lane & 15, kq = lane >> 4;
  const int srow = lane >> 3;
  const int schunk = ((lane & 7) - srow) & 7;
  const bf16* gA = A + (size_t)(m0 + wave * 32 + srow) * K + schunk * 8;
  const bf16* gB = BT + (size_t)(n0 + wave * 32 + srow) * K + schunk * 8;
  bf16* lA = &As[wave * 32 * 64];
  bf16* lB = &Bs[wave * 32 * 64];
  const size_t rstride = (size_t)8 * K;
  const int col0 = ((kq + l16) & 7) * 8;
  const int col1 = ((kq + 4 + l16) & 7) * 8;
  floatx4 acc[4][4];
  floatx4 zero = {0.f, 0.f, 0.f, 0.f};
#pragma unroll
  for (int i = 0; i < 4; ++i)
#pragma unroll
    for (int jj = 0; jj < 4; ++jj) acc[i][jj] = zero;

  for (int k0 = 0; k0 < K; k0 += 64) {
    __syncthreads();
#pragma unroll
    for (int i = 0; i < 4; ++i) {
      gl_lds16(gA + k0 + i * rstride, lA + i * 8 * 64);
      gl_lds16(gB + k0 + i * rstride, lB + i * 8 * 64);
    }
    __syncthreads();
#pragma unroll
    for (int ks = 0; ks < 2; ++ks) {
      const int col = ks ? col1 : col0;
      short8 af[4], bfr[4];
#pragma unroll
      for (int t = 0; t < 4; ++t) {
        af[t] = *reinterpret_cast<const short8*>(&As[(wm + t * 16 + l16) * 64 + col]);
        bfr[t] = *reinterpret_cast<const short8*>(&Bs[(wn + t * 16 + l16) * 64 + col]);
      }
#pragma unroll
      for (int mt = 0; mt < 4; ++mt)
#pragma unroll
        for (int nt = 0; nt < 4; ++nt)
          acc[mt][nt] = __builtin_amdgcn_mfma_f32_16x16x32_bf16(
              af[mt], bfr[nt], acc[mt][nt], 0, 0, 0);
    }
  }

  if (MODE == 4 || MODE == 5) {
    const int halfN = N >> 1;
#pragma unroll
    for (int mt = 0; mt < 4; ++mt) {
#pragma unroll
      for (int nt = 0; nt < 4; ++nt) {
        int nn = n0 + wn + nt * 16 + l16;
#pragma unroll
        for (int r = 0; r < 4; ++r) {
          float v = acc[mt][nt][r];
          float g = __shfl_xor(v, 1);
          if ((lane & 1) == 0) {
            int m = m0 + wm + mt * 16 + kq * 4 + r;
            float res = v * sigm(g);
            size_t o = (size_t)m * halfN + (nn >> 1);
            if (MODE == 4) outf[o] = res;
            else outb[o] = __float2bfloat16(res);
          }
        }
      }
    }
    return;
  }

#pragma unroll
  for (int mt = 0; mt < 4; ++mt) {
#pragma unroll
    for (int nt = 0; nt < 4; ++nt) {
      int n = n0 + wn + nt * 16 + l16;
      float bv = bias ? bias[n] : 0.f;
#pragma unroll
      for (int r = 0; r < 4; ++r) {
        int m = m0 + wm + mt * 16 + kq * 4 + r;
        float v = acc[mt][nt][r] + bv;
        size_t o = (size_t)m * N + n;
        if (MODE == 2) outf[o] = addin[o] + gate[m] * v;
        else if (MODE == 6) outb[o] = __float2bfloat16(addin[o] * sigm(v));
      }
    }
  }
}

// ---------------- memory q/kg/v/g projections ----------------
__global__ __launch_bounds__(256) void k_qkvg(
    const float* __restrict__ xh, const float* __restrict__ Wq,
    const float* __restrict__ Wk, const float* __restrict__ Wv,
    const float* __restrict__ gw, const float* __restrict__ gb,
    float* __restrict__ q, float* __restrict__ kg, float* __restrict__ v,
    float* __restrict__ gout) {
  __shared__ float xm[NMEM * HEADD];
  __shared__ float gsh[NMEM];
  int tok = blockIdx.x, tid = threadIdx.x;
  for (int i = tid; i < NMEM * HEADD; i += 256)
    xm[i] = xh[(size_t)tok * HDIM + 6 * HEADD + i];
  __syncthreads();
  if (tid < NMEM) {
    float a = gb[tid];
    for (int d = 0; d < HEADD; ++d) a += xm[tid * HEADD + d] * gw[tid * HEADD + d];
    float s = sigm(a);
    gsh[tid] = s;
    gout[tok * NMEM + tid] = s;
  }
  __syncthreads();
  for (int i = tid; i < 1280; i += 256) {
    if (i < 384) {
      int n = i / HEADD, e = i % HEADD;
      const float* W = Wq + (size_t)n * HEADD * HEADD + e;
      const float* xr = xm + n * HEADD;
      float a = 0.f;
      for (int d = 0; d < HEADD; ++d) a += xr[d] * W[(size_t)d * HEADD];
      q[(size_t)tok * 384 + i] = a;
    } else if (i < 768) {
      int i2 = i - 384;
      int n = i2 / HEADD, e = i2 % HEADD;
      const float* W = Wk + (size_t)n * HEADD * HEADD + e;
      const float* xr = xm + n * HEADD;
      float a = 0.f;
      for (int d = 0; d < HEADD; ++d) a += xr[d] * W[(size_t)d * HEADD];
      kg[(size_t)tok * 384 + i2] = a * gsh[n];
    } else {
      int i2 = i - 768;
      int n = i2 / MEMD, e = i2 % MEMD;
      const float* W = Wv + (size_t)n * HEADD * MEMD + e;
      const float* xr = xm + n * HEADD;
      float a = 0.f;
      for (int d = 0; d < HEADD; ++d) a += xr[d] * W[(size_t)d * MEMD];
      v[(size_t)tok * 512 + i2] = a;
    }
  }
}

// ---------------- chunk means of g ----------------
__global__ __launch_bounds__(256) void k_gmean(const float* __restrict__ g,
                                               float* __restrict__ ga) {
  int idx = blockIdx.x * 256 + threadIdx.x;
  if (idx >= 512) return;
  int b = idx >> 7, ch = (idx >> 2) & 31, n = idx & 3;
  float s = 0.f;
  for (int t = 0; t < 64; ++t)
    s += g[((size_t)b * SEQ + ch * 64 + t) * NMEM + n];
  ga[idx] = s * (1.0f / 64.0f);
}

// ---------------- pass 1: per-chunk writes W[bnc][96][128] ----------------
__global__ __launch_bounds__(256) void k_memW(const float* __restrict__ kg,
                                              const float* __restrict__ v,
                                              float* __restrict__ W) {
  __shared__ float X[64 * 96];
  __shared__ float V[64 * 128];
  int bx = blockIdx.x;
  int bn = bx >> 5, ch = bx & 31;
  int b = bn >> 2, n = bn & 3;
  int t0 = b * SEQ + ch * 64;
  int tid = threadIdx.x;
  for (int i = tid; i < 64 * 96; i += 256) {
    int s = i / 96, d = i % 96;
    X[i] = kg[((size_t)(t0 + s) * NMEM + n) * HEADD + d];
  }
  for (int i = tid; i < 64 * 128; i += 256) {
    int s = i >> 7, m = i & 127;
    V[i] = v[((size_t)(t0 + s) * NMEM + n) * MEMD + m];
  }
  __syncthreads();
  float* Wb = W + (size_t)bx * 96 * 128;
  for (int t = tid; t < 768; t += 256) {
    int d0 = (t >> 5) * 4, m0 = (t & 31) * 4;
    float acc[4][4] = {};
    for (int s = 0; s < 64; ++s) {
      float4 xv = *reinterpret_cast<const float4*>(&X[s * 96 + d0]);
      float4 vv = *reinterpret_cast<const float4*>(&V[s * 128 + m0]);
      float xa[4] = {xv.x, xv.y, xv.z, xv.w};
      float va[4] = {vv.x, vv.y, vv.z, vv.w};
#pragma unroll
      for (int a = 0; a < 4; ++a)
#pragma unroll
        for (int e = 0; e < 4; ++e) acc[a][e] += xa[a] * va[e];
    }
#pragma unroll
    for (int a = 0; a < 4; ++a) {
      float4 o = {acc[a][0], acc[a][1], acc[a][2], acc[a][3]};
      *reinterpret_cast<float4*>(&Wb[(size_t)(d0 + a) * 128 + m0]) = o;
    }
  }
}

// ---------------- pass 2: prefix scan over chunks ----------------
__global__ __launch_bounds__(256) void k_memscanM(const float* __restrict__ W,
                                                  const float* __restrict__ ga,
                                                  float* __restrict__ Mp) {
  int bx = blockIdx.x;
  int bn = bx / 48, j = bx % 48;
  int elem = j * 256 + threadIdx.x;
  int b = bn >> 2, n = bn & 3;
  float M = 0.f;
  for (int ch = 0; ch < 32; ++ch) {
    size_t base = ((size_t)bn * 32 + ch) * 12288 + elem;
    Mp[base] = M;
    float g = ga[(b * 32 + ch) * NMEM + n];
    M = (1.f - g) * M + W[base];
  }
}

// ---------------- pass 3: reads = q @ M_prefix ----------------
__global__ __launch_bounds__(256) void k_memR(const float* __restrict__ q,
                                              const float* __restrict__ Mp,
                                              float* __restrict__ rd) {
  extern __shared__ float smem[];
  float* Q = smem;
  float* Ms = smem + 64 * 96;
  int bx = blockIdx.x;
  int bn = bx >> 5, ch = bx & 31;
  int b = bn >> 2, n = bn & 3;
  int t0 = b * SEQ + ch * 64;
  int tid = threadIdx.x;
  for (int i = tid; i < 64 * 96; i += 256) {
    int s = i / 96, d = i % 96;
    Q[i] = q[((size_t)(t0 + s) * NMEM + n) * HEADD + d];
  }
  for (int i = tid; i < 96 * 128; i += 256)
    Ms[i] = Mp[((size_t)bn * 32 + ch) * 12288 + i];
  __syncthreads();
  for (int t = tid; t < 512; t += 256) {
    int s0 = (t >> 5) * 4, m0 = (t & 31) * 4;
    float acc[4][4] = {};
    for (int k = 0; k < 96; ++k) {
      float4 mv = *reinterpret_cast<const float4*>(&Ms[k * 128 + m0]);
      float ma[4] = {mv.x, mv.y, mv.z, mv.w};
#pragma unroll
      for (int si = 0; si < 4; ++si) {
        float qs = Q[(s0 + si) * 96 + k];
#pragma unroll
        for (int mi = 0; mi < 4; ++mi) acc[si][mi] += qs * ma[mi];
      }
    }
#pragma unroll
    for (int si = 0; si < 4; ++si) {
      float4 o = {acc[si][0], acc[si][1], acc[si][2], acc[si][3]};
      *reinterpret_cast<float4*>(
          &rd[((size_t)(t0 + s0 + si) * NMEM + n) * MEMD + m0]) = o;
    }
  }
}

// ---------------- combine: out = (hconv + memproj) * head_weight ----------------
__global__ __launch_bounds__(256) void k_combine(
    const float* __restrict__ hconv, const float* __restrict__ reads,
    const float* __restrict__ Wout, const float* __restrict__ hw,
    float* __restrict__ outf, bf16* __restrict__ outb) {
  __shared__ float rd[NMEM * MEMD];
  int tok = blockIdx.x, tid = threadIdx.x;
  for (int i = tid; i < NMEM * MEMD; i += 256)
    rd[i] = reads[(size_t)tok * NMEM * MEMD + i];
  __syncthreads();
  for (int c = tid; c < HDIM; c += 256) {
    int head = c / HEADD, hd = c % HEADD;
    float v = hconv[(size_t)tok * HDIM + c];
    if (head >= 6 && head < 10) {
      int n = head - 6;
      const float* W = Wout + (size_t)(n * MEMD) * HEADD + hd;
      for (int m2 = 0; m2 < MEMD; ++m2) v += rd[n * MEMD + m2] * W[(size_t)m2 * HEADD];
    }
    v *= hw[tok * NHEADS + head];
    outf[(size_t)tok * HDIM + c] = v;
    outb[(size_t)tok * HDIM + c] = __float2bfloat16(v);
  }
}

extern "C" void kernel_launch(void* const* d_in, const int* in_sizes, int n_in,
                              void* d_out, int out_size, void* d_ws,
                              size_t ws_size, hipStream_t stream) {
  const float* x_in = (const float*)d_in[0];
  const float* norm1_w = (const float*)d_in[1];
  const float* norm2_w = (const float*)d_in[2];
  const float* norm3_w = (const float*)d_in[3];
  const float* cs_w = (const float*)d_in[4];
  const float* cs_b = (const float*)d_in[5];
  const float* cs_proj_w = (const float*)d_in[6];
  const float* cs_proj_b = (const float*)d_in[7];
  const float* gate_proj_w = (const float*)d_in[8];
  const float* router_w = (const float*)d_in[9];
  const float* router_b = (const float*)d_in[10];
  const float* head_w = (const float*)d_in[11];
  const float* head_b = (const float*)d_in[12];
  const float* mem_q = (const float*)d_in[13];
  const float* mem_k = (const float*)d_in[14];
  const float* mem_v = (const float*)d_in[15];
  const float* mem_gw = (const float*)d_in[16];
  const float* mem_gb = (const float*)d_in[17];
  const float* mem_out = (const float*)d_in[18];
  const float* mixgate_w = (const float*)d_in[19];
  const float* mixgate_b = (const float*)d_in[20];
  const float* mixing_w = (const float*)d_in[21];
  const float* mixing_b = (const float*)d_in[22];
  const float* ffn_in_w = (const float*)d_in[23];
  const float* ffn_out_w = (const float*)d_in[24];
  const float* cg_w = (const float*)d_in[25];
  const float* cg_b = (const float*)d_in[26];
  const float* sg_w = (const float*)d_in[27];
  const float* sg_b = (const float*)d_in[28];
  const float* fg_w = (const float*)d_in[29];
  const float* fg_b = (const float*)d_in[30];
  float* out = (float*)d_out;

  char* wsp = (char*)d_ws;
  size_t off = 0;
  auto alloc = [&](size_t bytes) -> char* {
    char* p = wsp + off;
    off += (bytes + 255) & ~(size_t)255;
    return p;
  };
  bf16* NB = (bf16*)alloc((size_t)TOKENS * HDIM * 2);
  float* F1 = (float*)alloc((size_t)TOKENS * HDIM * 4);
  float* F2 = (float*)alloc((size_t)TOKENS * HDIM * 4);
  float* F3 = (float*)alloc((size_t)TOKENS * HDIM * 4);
  char* REG = alloc((size_t)TOKENS * FINNER * 2);
  float* qb = (float*)REG;
  float* kgb = (float*)(REG + (size_t)TOKENS * 384 * 4);
  float* vb = (float*)((char*)kgb + (size_t)TOKENS * 384 * 4);
  float* rdb = (float*)((char*)vb + (size_t)TOKENS * 512 * 4);
  bf16* XG = (bf16*)REG;   // stage-C view
  bf16* NB2 = (bf16*)REG;  // mixgate output view (qb region dead by then)
  bf16* NBc = (bf16*)REG;  // conv-stack output view (stage A only)
  bf16* WTcs = (bf16*)alloc((size_t)1152 * 1152 * 2);
  bf16* WTgp = (bf16*)alloc((size_t)2304 * 1152 * 2);
  bf16* WTmg = (bf16*)alloc((size_t)1152 * 1152 * 2);
  bf16* WTmx = (bf16*)alloc((size_t)1152 * 1152 * 2);
  float* G1 = (float*)alloc(TOKENS * 4);
  float* G2 = (float*)alloc(TOKENS * 4);
  float* G3 = (float*)alloc(TOKENS * 4);
  float* GM = (float*)alloc((size_t)TOKENS * NMEM * 4);
  float* GA = (float*)alloc(4 * 32 * NMEM * 4);
  float* HW = (float*)alloc((size_t)TOKENS * NHEADS * 4);
  bf16* WTfin = (bf16*)F1;
  bf16* WTfout = (bf16*)F2;
  float* Wbuf = F2;
  float* Mpref = F3;

  const int gE = (TOKENS * HDIM) / 256;

  k_transpose_bf16<<<dim3(36, 36), 256, 0, stream>>>(cs_proj_w, WTcs, 1152, 1152);
  k_transpose_pair<<<dim3(72, 36), 256, 0, stream>>>(gate_proj_w, WTgp, 1152, 2304);
  k_transpose_bf16<<<dim3(36, 36), 256, 0, stream>>>(mixgate_w, WTmg, 1152, 1152);
  k_transpose_bf16<<<dim3(36, 36), 256, 0, stream>>>(mixing_w, WTmx, 1152, 1152);

  // ---- stage A: conv stack ----
  k_rms_gate<<<TOKENS, 256, 0, stream>>>(x_in, norm1_w, cg_w, cg_b, NB, nullptr, G1,
                                         0, nullptr, nullptr, nullptr);
  k_convstack<<<2304, 256, 0, stream>>>(NB, NBc, cs_w, cs_b);
  k_gemm<2><<<dim3(9, 64), 256, 0, stream>>>(NBc, WTcs, cs_proj_b, G1, x_in, out,
                                             nullptr, TOKENS, 1152, 1152);

  // ---- stage B: multi-head state ----
  k_rms_gate<<<TOKENS, 256, 0, stream>>>(out, norm2_w, sg_w, sg_b, NB, nullptr, G2,
                                         0, router_w, router_b, HW);
  k_gemm<4><<<dim3(18, 64), 256, 0, stream>>>(NB, WTgp, nullptr, nullptr, nullptr,
                                              F3, nullptr, TOKENS, 2304, 1152);
  k_headconv<<<gE, 256, 0, stream>>>(F3, F1, head_w, head_b, 0);
  k_headconv<<<gE, 256, 0, stream>>>(F1, F2, head_w, head_b, 1);
  k_headconv<<<gE, 256, 0, stream>>>(F2, F1, head_w, head_b, 2);
  k_qkvg<<<TOKENS, 256, 0, stream>>>(F3, mem_q, mem_k, mem_v, mem_gw, mem_gb,
                                     qb, kgb, vb, GM);
  k_gmean<<<2, 256, 0, stream>>>(GM, GA);
  k_memW<<<512, 256, 0, stream>>>(kgb, vb, Wbuf);
  k_memscanM<<<768, 256, 0, stream>>>(Wbuf, GA, Mpref);
  k_memR<<<512, 256, (64 * 96 + 96 * 128) * 4, stream>>>(qb, Mpref, rdb);
  k_combine<<<TOKENS, 256, 0, stream>>>(F1, rdb, mem_out, HW, F2, NB);
  // fused mixgate: NB2 = bf16(F2 * sigm(NB@mixgate + b))
  k_gemm<6><<<dim3(9, 64), 256, 0, stream>>>(NB, WTmg, mixgate_b, nullptr, F2,
                                             nullptr, NB2, TOKENS, 1152, 1152);
  k_gemm<2><<<dim3(9, 64), 256, 0, stream>>>(NB2, WTmx, mixing_b, G2, out, out,
                                             nullptr, TOKENS, 1152, 1152);

  // ---- stage C: GLU FFN ----
  k_rms_gate<<<TOKENS, 256, 0, stream>>>(out, norm3_w, fg_w, fg_b, NB, nullptr, G3,
                                         0, nullptr, nullptr, nullptr);
  k_transpose_pair<<<dim3(288, 36), 256, 0, stream>>>(ffn_in_w, WTfin, 1152, 9216);
  k_transpose_bf16<<<dim3(36, 144), 256, 0, stream>>>(ffn_out_w, WTfout, 4608, 1152);
  k_gemm<5><<<dim3(72, 64), 256, 0, stream>>>(NB, WTfin, nullptr, nullptr, nullptr,
                                              nullptr, XG, TOKENS, 9216, 1152);
  k_gemm<2><<<dim3(9, 64), 256, 0, stream>>>(XG, WTfout, nullptr, G3, out, out,
                                             nullptr, TOKENS, 1152, 4608);
}